// Round 7
// baseline (4536.250 us; speedup 1.0000x reference)
//
#include <hip/hip_runtime.h>
#include <hip/hip_bf16.h>
#include <hip/hip_cooperative_groups.h>

namespace cg = cooperative_groups;

#define NB   256
#define NT   32
#define NV   10000
#define NVP  10240
#define NDF  1280
#define NH   512
#define VT_N 40      // vocab col tiles of 256

typedef short bf16x8 __attribute__((ext_vector_type(8)));
typedef float f32x4  __attribute__((ext_vector_type(4)));
typedef unsigned short u16;

__device__ __forceinline__ float b2f(u16 u) {
    union { unsigned i; float f; } v; v.i = ((unsigned)u) << 16; return v.f;
}
__device__ __forceinline__ u16 f2b(float f) {
    union { float f; unsigned i; } v; v.f = f;
    unsigned r = v.i + 0x7FFF + ((v.i >> 16) & 1);   // RNE
    return (u16)(r >> 16);
}

// ---------------- workspace layout (byte offsets, 16-aligned) --------------
static const size_t B_C     = 0;                                  // [256][512] f32 cell
static const size_t B_HP    = B_C     + (size_t)256*512*4;        // h0 f32 (proj out)
static const size_t B_PMAX  = B_HP    + (size_t)256*512*4;        // [8192][40] f32
static const size_t B_PSUM  = B_PMAX  + (size_t)8192*VT_N*4;      // [8192][40] f32
static const size_t B_TGT   = B_PSUM  + (size_t)8192*VT_N*4;      // [8192] f32
static const size_t B_LOSS  = B_TGT   + (size_t)8192*4;           // [1] f32
static const size_t B_AB    = B_LOSS  + 16;                       // [256][16][512] bf16
static const size_t B_XPB   = B_AB    + (size_t)256*16*512*2;     // [32][256][2048] bf16
static const size_t B_HALLB = B_XPB   + (size_t)32*256*2048*2;    // [32][256][512] bf16
static const size_t B_WVT   = B_HALLB + (size_t)32*256*512*2;     // [10240][512] bf16
static const size_t B_WXT   = B_WVT   + (size_t)10240*512*2;      // [2048][256] bf16
static const size_t B_WHAT  = B_WXT   + (size_t)2048*256*2;       // [2048][1024] bf16
static const size_t B_HX0   = B_WHAT  + (size_t)2048*1024*2;      // [256][1024] bf16
static const size_t B_HX1   = B_HX0   + (size_t)256*1024*2;       // [256][1024] bf16

// ---------------------------------------------------------------------------
// T0: transpose+convert: src f32 [K][N] -> dst bf16 [Npad][ldK] at koff.
__global__ __launch_bounds__(256) void tconv_kernel(
    const float* __restrict__ src, u16* __restrict__ dst,
    int K, int N, int Npad, int ldK, int koff)
{
    __shared__ u16 tile[64][65];
    const int k0 = blockIdx.y * 64, n0 = blockIdx.x * 64, tid = threadIdx.x;
#pragma unroll
    for (int i = 0; i < 16; i++) {
        int idx = tid + i * 256;
        int kk = idx >> 6, nn = idx & 63;
        int n = n0 + nn;
        float v = (n < N) ? src[(size_t)(k0 + kk) * N + n] : 0.f;
        tile[kk][nn] = f2b(v);
    }
    __syncthreads();
#pragma unroll
    for (int i = 0; i < 16; i++) {
        int idx = tid + i * 256;
        int nn = idx >> 6, kk = idx & 63;
        int n = n0 + nn;
        if (n < Npad) dst[(size_t)n * ldK + koff + k0 + kk] = tile[kk][nn];
    }
}

// ---------------------------------------------------------------------------
// K1: A = feats.Wp + bp (bf16), h0=c0=mean_p A (f32); h0 bf16 -> hx0
__global__ __launch_bounds__(256) void proj_kernel(
    const float* __restrict__ feats, const float* __restrict__ Wp,
    const float* __restrict__ bp, u16* __restrict__ Ab,
    float* __restrict__ h0, float* __restrict__ c0, u16* __restrict__ hx0)
{
    const int n = blockIdx.x, tid = threadIdx.x;
    __shared__ float fl[64][16];
    float acc0[16], acc1[16];
#pragma unroll
    for (int p = 0; p < 16; p++) { acc0[p] = 0.f; acc1[p] = 0.f; }
    const float* fn = feats + (size_t)n * (NDF * 16);
    const int l = tid * 4, cc = l >> 4, ij = l & 15;
    for (int c0i = 0; c0i < NDF; c0i += 64) {
        __syncthreads();
        float4 v = *(const float4*)(fn + (c0i + cc) * 16 + ij);
        fl[cc][ij] = v.x; fl[cc][ij+1] = v.y; fl[cc][ij+2] = v.z; fl[cc][ij+3] = v.w;
        __syncthreads();
        for (int c2 = 0; c2 < 64; c2++) {
            float w0 = Wp[(size_t)(c0i + c2) * NH + tid];
            float w1 = Wp[(size_t)(c0i + c2) * NH + tid + 256];
#pragma unroll
            for (int p = 0; p < 16; p++) {
                float f = fl[c2][p];
                acc0[p] += f * w0;
                acc1[p] += f * w1;
            }
        }
    }
    float bp0 = bp[tid], bp1 = bp[tid + 256];
    float s0 = 0.f, s1 = 0.f;
#pragma unroll
    for (int p = 0; p < 16; p++) {
        float a0 = acc0[p] + bp0, a1 = acc1[p] + bp1;
        Ab[(size_t)n * 8192 + p * 512 + tid]       = f2b(a0);
        Ab[(size_t)n * 8192 + p * 512 + tid + 256] = f2b(a1);
        s0 += a0; s1 += a1;
    }
    s0 *= 0.0625f; s1 *= 0.0625f;
    h0[n * 512 + tid] = s0;  h0[n * 512 + tid + 256] = s1;
    c0[n * 512 + tid] = s0;  c0[n * 512 + tid + 256] = s1;
    hx0[(size_t)n * 1024 + tid]       = f2b(s0);
    hx0[(size_t)n * 1024 + tid + 256] = f2b(s1);
}

// ---------------------------------------------------------------------------
// K2 (MFMA): xpb = embed@Wx + b  (bf16)
__global__ __launch_bounds__(256) void xp_mfma_kernel(
    const int* __restrict__ caps, const float* __restrict__ We,
    const u16* __restrict__ Wxt, const float* __restrict__ bb,
    u16* __restrict__ xpb)
{
    const int ct = blockIdx.x, rt = blockIdx.y;
    const int tid = threadIdx.x, w = tid >> 6, lane = tid & 63;
    const int r0 = rt * 64;
    const int lm = lane & 15, lkq = lane >> 4, lk = lkq * 8;
    const int nbase = ct * 512 + w * 128;

    int capm[4];
#pragma unroll
    for (int mt = 0; mt < 4; mt++) {
        int row = r0 + mt * 16 + lm;
        capm[mt] = caps[(row >> 5) * 33 + (row & 31)];
    }
    f32x4 acc[4][8];
#pragma unroll
    for (int mt = 0; mt < 4; mt++)
#pragma unroll
        for (int nt = 0; nt < 8; nt++) acc[mt][nt] = (f32x4){0.f, 0.f, 0.f, 0.f};

    for (int kc = 0; kc < 256; kc += 32) {
        bf16x8 af[4];
#pragma unroll
        for (int mt = 0; mt < 4; mt++) {
            const float* ap = We + (size_t)capm[mt] * 256 + kc + lk;
            float4 f0 = *(const float4*)ap;
            float4 f1 = *(const float4*)(ap + 4);
            bf16x8 t;
            t[0] = (short)f2b(f0.x); t[1] = (short)f2b(f0.y);
            t[2] = (short)f2b(f0.z); t[3] = (short)f2b(f0.w);
            t[4] = (short)f2b(f1.x); t[5] = (short)f2b(f1.y);
            t[6] = (short)f2b(f1.z); t[7] = (short)f2b(f1.w);
            af[mt] = t;
        }
#pragma unroll
        for (int nt = 0; nt < 8; nt++) {
            bf16x8 bfg = *(const bf16x8*)(Wxt + (size_t)(nbase + nt * 16 + lm) * 256 + kc + lk);
#pragma unroll
            for (int mt = 0; mt < 4; mt++)
                acc[mt][nt] = __builtin_amdgcn_mfma_f32_16x16x32_bf16(af[mt], bfg, acc[mt][nt], 0, 0, 0);
        }
    }
    float bbv[8];
#pragma unroll
    for (int nt = 0; nt < 8; nt++) bbv[nt] = bb[nbase + nt * 16 + lm];
#pragma unroll
    for (int mt = 0; mt < 4; mt++)
#pragma unroll
        for (int nt = 0; nt < 8; nt++)
#pragma unroll
            for (int r = 0; r < 4; r++) {
                int row = r0 + mt * 16 + lkq * 4 + r;   // row = n*32 + t
                int col = nbase + nt * 16 + lm;
                float v = acc[mt][nt][r] + bbv[nt];
                xpb[((size_t)(row & 31) * 256 + (row >> 5)) * 2048 + col] = f2b(v);
            }
}

// ---------------------------------------------------------------------------
// K3 (cooperative, persistent): full 32-step recurrence.
// 256 blocks x 256 thr. Per step: phase A attention (block b = row b, LDS
// A-cache) -> grid.sync -> phase B gates (1024 wave-tasks: 512 tiles x K/2,
// LDS pair-reduce, epilogue) -> grid.sync.
__global__ __launch_bounds__(256) void lstm_seq_kernel(
    const u16* __restrict__ Ab, const u16* __restrict__ what,
    const u16* __restrict__ xpb, float* __restrict__ c,
    u16* __restrict__ hx0, u16* __restrict__ hx1,
    u16* __restrict__ hallb)
{
    cg::grid_group gg = cg::this_grid();
    const int b = blockIdx.x, tid = threadIdx.x;
    const int w = tid >> 6, lane = tid & 63;
    const int lm = lane & 15, lkq = lane >> 4, lk = lkq * 8;

    __shared__ u16 As[16 * 512];      // A[n=b] cache, resident all 32 steps
    __shared__ u16 hsm[512];
    __shared__ float scred[16];
    __shared__ float wts[16];
    __shared__ float gred[2][4][64][4];

    {   // load A-cache once
        const u16* src = Ab + (size_t)b * 8192;
        for (int i = tid * 4; i < 8192; i += 1024)
            *(ushort4*)&As[i] = *(const ushort4*)(src + i);
    }

    const int gw = b * 4 + w;          // global wave id 0..1023
    const int tile = gw >> 1;          // 0..511
    const int khalf = gw & 1;
    const int mt = tile >> 5, hct = tile & 31;
    const int r0g = mt * 16;
    const int kbase = khalf * 512;

    for (int t = 0; t < NT; t++) {
        u16* hx_in  = (t & 1) ? hx1 : hx0;
        u16* hx_out = (t & 1) ? hx0 : hx1;

        __syncthreads();
        // ---- Phase A: attention for n=b ----
        if (tid < 128)
            *(ushort4*)&hsm[tid * 4] = *(const ushort4*)(hx_in + (size_t)b * 1024 + tid * 4);
        __syncthreads();
        {
            const int p = tid >> 4, seg = tid & 15;
            const u16* ap = &As[p * 512 + seg * 32];
            const u16* hp = &hsm[seg * 32];
            float s = 0.f;
#pragma unroll
            for (int j = 0; j < 32; j += 4) {
                ushort4 a4 = *(const ushort4*)(ap + j);
                ushort4 h4 = *(const ushort4*)(hp + j);
                s += b2f(a4.x)*b2f(h4.x) + b2f(a4.y)*b2f(h4.y)
                   + b2f(a4.z)*b2f(h4.z) + b2f(a4.w)*b2f(h4.w);
            }
#pragma unroll
            for (int mask = 1; mask <= 8; mask <<= 1) s += __shfl_xor(s, mask, 64);
            if (seg == 0) scred[p] = s * 0.04419417382415922f;
        }
        __syncthreads();
        if (tid < 16) {
            float s = scred[tid];
            float m = s;
#pragma unroll
            for (int mask = 1; mask <= 8; mask <<= 1) m = fmaxf(m, __shfl_xor(m, mask, 64));
            float e = __expf(s - m);
            float su = e;
#pragma unroll
            for (int mask = 1; mask <= 8; mask <<= 1) su += __shfl_xor(su, mask, 64);
            wts[tid] = e / su;
        }
        __syncthreads();
        {
            const int d = tid * 2;
            float a0 = 0.f, a1 = 0.f;
#pragma unroll
            for (int p = 0; p < 16; p++) {
                float wp = wts[p];
                unsigned pr = *(const unsigned*)&As[p * 512 + d];
                a0 += wp * b2f((u16)(pr & 0xffff));
                a1 += wp * b2f((u16)(pr >> 16));
            }
            unsigned o = ((unsigned)f2b(a1) << 16) | (unsigned)f2b(a0);
            *(unsigned*)(hx_in + (size_t)b * 1024 + 512 + d) = o;
        }
        __threadfence();
        gg.sync();

        // ---- Phase B: gates ----
        f32x4 acc[4];
#pragma unroll
        for (int ty = 0; ty < 4; ty++) acc[ty] = (f32x4){0.f, 0.f, 0.f, 0.f};
        const u16* arow = hx_in + (size_t)(r0g + lm) * 1024 + kbase + lk;
        const u16* brow = what + (size_t)(hct * 16 + lm) * 1024 + kbase + lk;
        for (int kc = 0; kc < 512; kc += 32) {
            bf16x8 af = *(const bf16x8*)(arow + kc);
#pragma unroll
            for (int ty = 0; ty < 4; ty++) {
                bf16x8 bfg = *(const bf16x8*)(brow + (size_t)ty * 512 * 1024 + kc);
                acc[ty] = __builtin_amdgcn_mfma_f32_16x16x32_bf16(af, bfg, acc[ty], 0, 0, 0);
            }
        }
        if (khalf == 1) {
#pragma unroll
            for (int ty = 0; ty < 4; ty++)
#pragma unroll
                for (int r = 0; r < 4; r++) gred[w >> 1][ty][lane][r] = acc[ty][r];
        }
        __syncthreads();
        if (khalf == 0) {
            const int pr = w >> 1;
#pragma unroll
            for (int r = 0; r < 4; r++) {
                const int n = r0g + lkq * 4 + r;
                const int hcol = hct * 16 + lm;
                const u16* xq = xpb + (size_t)t * 524288 + (size_t)n * 2048;
                float ai  = acc[0][r] + gred[pr][0][lane][r] + b2f(xq[hcol]);
                float af_ = acc[1][r] + gred[pr][1][lane][r] + b2f(xq[512 + hcol]);
                float ao  = acc[2][r] + gred[pr][2][lane][r] + b2f(xq[1024 + hcol]);
                float ag  = acc[3][r] + gred[pr][3][lane][r] + b2f(xq[1536 + hcol]);
                float ig = 1.f / (1.f + __expf(-ai));
                float fg = 1.f / (1.f + __expf(-af_));
                float og = 1.f / (1.f + __expf(-ao));
                float gv = tanhf(ag);
                const int idx = n * 512 + hcol;
                float cn = fg * c[idx] + ig * gv;
                float hn = og * tanhf(cn);
                c[idx] = cn;
                u16 hb = f2b(hn);
                hx_out[(size_t)n * 1024 + hcol] = hb;
                hallb[(size_t)t * 131072 + idx] = hb;
            }
        }
        __threadfence();
        gg.sync();
    }
}

// ---------------------------------------------------------------------------
// K4 (MFMA): vocab scores + fused logsumexp partials + target extract.
// 4x4 acc tile (higher occupancy). grid (40 vt of 256 cols, 128 rt of 64 rows).
__global__ __launch_bounds__(256) void vocab_mfma_kernel(
    const u16* __restrict__ hallb, const u16* __restrict__ Wvt,
    const float* __restrict__ bv, const int* __restrict__ caps,
    float* __restrict__ pmax, float* __restrict__ psum, float* __restrict__ tgt)
{
    const int vt = blockIdx.x, rt = blockIdx.y;
    const int tid = threadIdx.x, w = tid >> 6, lane = tid & 63;
    const int r0 = rt * 64;
    const int lm = lane & 15, lkq = lane >> 4, lk = lkq * 8;
    const int nbase = vt * 256 + w * 64;

    __shared__ int tvs[64];
    __shared__ float cm[64][4], cs[64][4];
    if (tid < 64) {
        int row = r0 + tid;                              // row = t*256 + n
        tvs[tid] = caps[(row & 255) * 33 + (row >> 8) + 1];
    }

    f32x4 acc[4][4];
#pragma unroll
    for (int mt = 0; mt < 4; mt++)
#pragma unroll
        for (int nt = 0; nt < 4; nt++) acc[mt][nt] = (f32x4){0.f, 0.f, 0.f, 0.f};

    for (int kc = 0; kc < 512; kc += 32) {
        bf16x8 af[4];
#pragma unroll
        for (int mt = 0; mt < 4; mt++)
            af[mt] = *(const bf16x8*)(hallb + (size_t)(r0 + mt * 16 + lm) * 512 + kc + lk);
#pragma unroll
        for (int nt = 0; nt < 4; nt++) {
            bf16x8 bfg = *(const bf16x8*)(Wvt + (size_t)(nbase + nt * 16 + lm) * 512 + kc + lk);
#pragma unroll
            for (int mt = 0; mt < 4; mt++)
                acc[mt][nt] = __builtin_amdgcn_mfma_f32_16x16x32_bf16(af[mt], bfg, acc[mt][nt], 0, 0, 0);
        }
    }
    __syncthreads();

    float bvv[4]; bool vld[4];
#pragma unroll
    for (int nt = 0; nt < 4; nt++) {
        int col = nbase + nt * 16 + lm;
        vld[nt] = (col < NV);
        bvv[nt] = vld[nt] ? bv[col] : 0.f;
    }
#pragma unroll
    for (int mt = 0; mt < 4; mt++)
#pragma unroll
        for (int r = 0; r < 4; r++) {
            int rloc = mt * 16 + lkq * 4 + r;
            int row = r0 + rloc;
            int tv = tvs[rloc];
            float vals[4]; float m = -1e30f;
#pragma unroll
            for (int nt = 0; nt < 4; nt++) {
                int col = nbase + nt * 16 + lm;
                float v = vld[nt] ? (acc[mt][nt][r] + bvv[nt]) : -1e30f;
                vals[nt] = v;
                m = fmaxf(m, v);
                if (col == tv) tgt[row] = v;
            }
#pragma unroll
            for (int mask = 1; mask <= 8; mask <<= 1) m = fmaxf(m, __shfl_xor(m, mask, 64));
            float s = 0.f;
#pragma unroll
            for (int nt = 0; nt < 4; nt++) s += __expf(vals[nt] - m);
#pragma unroll
            for (int mask = 1; mask <= 8; mask <<= 1) s += __shfl_xor(s, mask, 64);
            if (lm == 0) { cm[rloc][w] = m; cs[rloc][w] = s; }
        }
    __syncthreads();
    if (tid < 64) {
        int row = r0 + tid;
        float M = fmaxf(fmaxf(cm[tid][0], cm[tid][1]), fmaxf(cm[tid][2], cm[tid][3]));
        float S = cs[tid][0] * __expf(cm[tid][0] - M) + cs[tid][1] * __expf(cm[tid][1] - M)
                + cs[tid][2] * __expf(cm[tid][2] - M) + cs[tid][3] * __expf(cm[tid][3] - M);
        pmax[row * VT_N + vt] = M;
        psum[row * VT_N + vt] = S;
    }
}

// ---------------------------------------------------------------------------
__global__ __launch_bounds__(256) void loss_reduce_kernel(
    const float* __restrict__ pmax, const float* __restrict__ psum,
    const float* __restrict__ tgt, const int* __restrict__ caps,
    float* __restrict__ loss)
{
    const int row = blockIdx.x * 256 + threadIdx.x;
    float nll = 0.f;
    const int t = row >> 8, n = row & 255;
    const int tv = caps[n * 33 + t + 1];
    if (tv != 0) {
        float M = -1e30f;
#pragma unroll
        for (int vt = 0; vt < VT_N; vt++) M = fmaxf(M, pmax[row * VT_N + vt]);
        float S = 0.f;
#pragma unroll
        for (int vt = 0; vt < VT_N; vt++) S += psum[row * VT_N + vt] * __expf(pmax[row * VT_N + vt] - M);
        nll = logf(S) + M - tgt[row];
    }
#pragma unroll
    for (int off = 32; off; off >>= 1) nll += __shfl_down(nll, off, 64);
    __shared__ float r4[4];
    if ((threadIdx.x & 63) == 0) r4[threadIdx.x >> 6] = nll;
    __syncthreads();
    if (threadIdx.x == 0)
        atomicAdd(loss, (r4[0] + r4[1] + r4[2] + r4[3]) * (1.f / 256.f));
}

__global__ void finalize_kernel(const float* __restrict__ loss, float* __restrict__ out)
{
    if (threadIdx.x == 0 && blockIdx.x == 0) out[0] = loss[0];
}

// ---------------------------------------------------------------------------
extern "C" void kernel_launch(void* const* d_in, const int* in_sizes, int n_in,
                              void* d_out, int out_size, void* d_ws, size_t ws_size,
                              hipStream_t stream) {
    const float* feats = (const float*)d_in[0];
    const int*   caps  = (const int*)d_in[1];
    const float* Wp    = (const float*)d_in[2];
    const float* bp    = (const float*)d_in[3];
    const float* We    = (const float*)d_in[4];
    const float* Wx    = (const float*)d_in[5];
    const float* Wh    = (const float*)d_in[6];
    const float* Wattn = (const float*)d_in[7];
    const float* bb    = (const float*)d_in[8];
    const float* Wv    = (const float*)d_in[9];
    const float* bv    = (const float*)d_in[10];

    char* ws = (char*)d_ws;
    float* c     = (float*)(ws + B_C);
    float* h0f   = (float*)(ws + B_HP);
    float* pmax  = (float*)(ws + B_PMAX);
    float* psum  = (float*)(ws + B_PSUM);
    float* tgt   = (float*)(ws + B_TGT);
    float* loss  = (float*)(ws + B_LOSS);
    u16*   Ab    = (u16*)(ws + B_AB);
    u16*   xpb   = (u16*)(ws + B_XPB);
    u16*   hallb = (u16*)(ws + B_HALLB);
    u16*   wvt   = (u16*)(ws + B_WVT);
    u16*   wxt   = (u16*)(ws + B_WXT);
    u16*   what  = (u16*)(ws + B_WHAT);
    u16*   hx0   = (u16*)(ws + B_HX0);
    u16*   hx1   = (u16*)(ws + B_HX1);

    hipMemsetAsync(loss, 0, sizeof(float), stream);

    tconv_kernel<<<dim3(160, 8), 256, 0, stream>>>(Wv, wvt, 512, NV, NVP, 512, 0);
    tconv_kernel<<<dim3(32, 4),  256, 0, stream>>>(Wx, wxt, 256, 2048, 2048, 256, 0);
    tconv_kernel<<<dim3(32, 8),  256, 0, stream>>>(Wh, what, 512, 2048, 2048, 1024, 0);
    tconv_kernel<<<dim3(32, 8),  256, 0, stream>>>(Wattn, what, 512, 2048, 2048, 1024, 512);
    proj_kernel<<<256, 256, 0, stream>>>(feats, Wp, bp, Ab, h0f, c, hx0);
    xp_mfma_kernel<<<dim3(4, 128), 256, 0, stream>>>(caps, We, wxt, bb, xpb);

    {
        void* args[] = { (void*)&Ab, (void*)&what, (void*)&xpb, (void*)&c,
                         (void*)&hx0, (void*)&hx1, (void*)&hallb };
        hipLaunchCooperativeKernel((void*)lstm_seq_kernel, dim3(256), dim3(256),
                                   args, 0, stream);
    }

    vocab_mfma_kernel<<<dim3(VT_N, 128), 256, 0, stream>>>(
        hallb, wvt, bv, caps, pmax, psum, tgt);
    loss_reduce_kernel<<<32, 256, 0, stream>>>(pmax, psum, tgt, caps, loss);
    finalize_kernel<<<1, 64, 0, stream>>>(loss, (float*)d_out);
}

// Round 8
// 1272.476 us; speedup vs baseline: 3.5649x; 3.5649x over previous
//
#include <hip/hip_runtime.h>
#include <hip/hip_bf16.h>

#define NB   256
#define NT   32
#define NV   10000
#define NVP  10240
#define NDF  1280
#define NH   512
#define VT_N 20      // vocab col tiles of 512

typedef short bf16x8 __attribute__((ext_vector_type(8)));
typedef float f32x4  __attribute__((ext_vector_type(4)));
typedef unsigned short u16;

__device__ __forceinline__ float b2f(u16 u) {
    union { unsigned i; float f; } v; v.i = ((unsigned)u) << 16; return v.f;
}
__device__ __forceinline__ u16 f2b(float f) {
    union { float f; unsigned i; } v; v.f = f;
    unsigned r = v.i + 0x7FFF + ((v.i >> 16) & 1);   // RNE
    return (u16)(r >> 16);
}

// ---------------- workspace layout (byte offsets, 16-aligned) --------------
static const size_t B_C     = 0;                                  // [256][512] f32 cell
static const size_t B_PMAX  = B_C     + (size_t)256*512*4;        // [8192][20] f32
static const size_t B_PSUM  = B_PMAX  + (size_t)8192*VT_N*4;      // [8192][20] f32
static const size_t B_TGT   = B_PSUM  + (size_t)8192*VT_N*4;      // [8192] f32
static const size_t B_LOSS  = B_TGT   + (size_t)8192*4;           // [1] f32
static const size_t B_AB    = B_LOSS  + 16;                       // [256][16][512] bf16
static const size_t B_XPB   = B_AB    + (size_t)256*16*512*2;     // [32][256][2048] bf16
static const size_t B_HALLB = B_XPB   + (size_t)32*256*2048*2;    // [32][256][512] bf16
static const size_t B_WVT   = B_HALLB + (size_t)32*256*512*2;     // [10240][512] bf16
static const size_t B_WXT   = B_WVT   + (size_t)10240*512*2;      // [2048][256] bf16
static const size_t B_WHAT  = B_WXT   + (size_t)2048*256*2;       // [2048][1024] bf16
static const size_t B_HX0   = B_WHAT  + (size_t)2048*1024*2;      // [256][1024] bf16
static const size_t B_HX1   = B_HX0   + (size_t)256*1024*2;       // [256][1024] bf16

// ---------------------------------------------------------------------------
// T0: transpose+convert: src f32 [K][N] -> dst bf16 [Npad][ldK] at koff.
__global__ __launch_bounds__(256) void tconv_kernel(
    const float* __restrict__ src, u16* __restrict__ dst,
    int K, int N, int Npad, int ldK, int koff)
{
    __shared__ u16 tile[64][65];
    const int k0 = blockIdx.y * 64, n0 = blockIdx.x * 64, tid = threadIdx.x;
#pragma unroll
    for (int i = 0; i < 16; i++) {
        int idx = tid + i * 256;
        int kk = idx >> 6, nn = idx & 63;
        int n = n0 + nn;
        float v = (n < N) ? src[(size_t)(k0 + kk) * N + n] : 0.f;
        tile[kk][nn] = f2b(v);
    }
    __syncthreads();
#pragma unroll
    for (int i = 0; i < 16; i++) {
        int idx = tid + i * 256;
        int nn = idx >> 6, kk = idx & 63;
        int n = n0 + nn;
        if (n < Npad) dst[(size_t)n * ldK + koff + k0 + kk] = tile[kk][nn];
    }
}

// ---------------------------------------------------------------------------
// K1: A = feats.Wp + bp (bf16), c0 = mean_p A (f32); h0 bf16 -> hx0[0:512]
__global__ __launch_bounds__(256) void proj_kernel(
    const float* __restrict__ feats, const float* __restrict__ Wp,
    const float* __restrict__ bp, u16* __restrict__ Ab,
    float* __restrict__ c0, u16* __restrict__ hx0)
{
    const int n = blockIdx.x, tid = threadIdx.x;
    __shared__ float fl[64][16];
    float acc0[16], acc1[16];
#pragma unroll
    for (int p = 0; p < 16; p++) { acc0[p] = 0.f; acc1[p] = 0.f; }
    const float* fn = feats + (size_t)n * (NDF * 16);
    const int l = tid * 4, cc = l >> 4, ij = l & 15;
    for (int c0i = 0; c0i < NDF; c0i += 64) {
        __syncthreads();
        float4 v = *(const float4*)(fn + (c0i + cc) * 16 + ij);
        fl[cc][ij] = v.x; fl[cc][ij+1] = v.y; fl[cc][ij+2] = v.z; fl[cc][ij+3] = v.w;
        __syncthreads();
        for (int c2 = 0; c2 < 64; c2++) {
            float w0 = Wp[(size_t)(c0i + c2) * NH + tid];
            float w1 = Wp[(size_t)(c0i + c2) * NH + tid + 256];
#pragma unroll
            for (int p = 0; p < 16; p++) {
                float f = fl[c2][p];
                acc0[p] += f * w0;
                acc1[p] += f * w1;
            }
        }
    }
    float bp0 = bp[tid], bp1 = bp[tid + 256];
    float s0 = 0.f, s1 = 0.f;
#pragma unroll
    for (int p = 0; p < 16; p++) {
        float a0 = acc0[p] + bp0, a1 = acc1[p] + bp1;
        Ab[(size_t)n * 8192 + p * 512 + tid]       = f2b(a0);
        Ab[(size_t)n * 8192 + p * 512 + tid + 256] = f2b(a1);
        s0 += a0; s1 += a1;
    }
    s0 *= 0.0625f; s1 *= 0.0625f;
    c0[n * 512 + tid] = s0;  c0[n * 512 + tid + 256] = s1;
    hx0[(size_t)n * 1024 + tid]       = f2b(s0);
    hx0[(size_t)n * 1024 + tid + 256] = f2b(s1);
}

// ---------------------------------------------------------------------------
// K2 (MFMA): xpb = embed@Wx + b  (bf16), rows stored as [t][n]
__global__ __launch_bounds__(256) void xp_mfma_kernel(
    const int* __restrict__ caps, const float* __restrict__ We,
    const u16* __restrict__ Wxt, const float* __restrict__ bb,
    u16* __restrict__ xpb)
{
    const int ct = blockIdx.x, rt = blockIdx.y;
    const int tid = threadIdx.x, w = tid >> 6, lane = tid & 63;
    const int r0 = rt * 64;
    const int lm = lane & 15, lkq = lane >> 4, lk = lkq * 8;
    const int nbase = ct * 512 + w * 128;

    int capm[4];
#pragma unroll
    for (int mt = 0; mt < 4; mt++) {
        int row = r0 + mt * 16 + lm;
        capm[mt] = caps[(row >> 5) * 33 + (row & 31)];
    }
    f32x4 acc[4][8];
#pragma unroll
    for (int mt = 0; mt < 4; mt++)
#pragma unroll
        for (int nt = 0; nt < 8; nt++) acc[mt][nt] = (f32x4){0.f, 0.f, 0.f, 0.f};

    for (int kc = 0; kc < 256; kc += 32) {
        bf16x8 af[4];
#pragma unroll
        for (int mt = 0; mt < 4; mt++) {
            const float* ap = We + (size_t)capm[mt] * 256 + kc + lk;
            float4 f0 = *(const float4*)ap;
            float4 f1 = *(const float4*)(ap + 4);
            bf16x8 t;
            t[0] = (short)f2b(f0.x); t[1] = (short)f2b(f0.y);
            t[2] = (short)f2b(f0.z); t[3] = (short)f2b(f0.w);
            t[4] = (short)f2b(f1.x); t[5] = (short)f2b(f1.y);
            t[6] = (short)f2b(f1.z); t[7] = (short)f2b(f1.w);
            af[mt] = t;
        }
#pragma unroll
        for (int nt = 0; nt < 8; nt++) {
            bf16x8 bfg = *(const bf16x8*)(Wxt + (size_t)(nbase + nt * 16 + lm) * 256 + kc + lk);
#pragma unroll
            for (int mt = 0; mt < 4; mt++)
                acc[mt][nt] = __builtin_amdgcn_mfma_f32_16x16x32_bf16(af[mt], bfg, acc[mt][nt], 0, 0, 0);
        }
    }
    float bbv[8];
#pragma unroll
    for (int nt = 0; nt < 8; nt++) bbv[nt] = bb[nbase + nt * 16 + lm];
#pragma unroll
    for (int mt = 0; mt < 4; mt++)
#pragma unroll
        for (int nt = 0; nt < 8; nt++)
#pragma unroll
            for (int r = 0; r < 4; r++) {
                int row = r0 + mt * 16 + lkq * 4 + r;   // row = n*32 + t
                int col = nbase + nt * 16 + lm;
                float v = acc[mt][nt][r] + bbv[nt];
                xpb[((size_t)(row & 31) * 256 + (row >> 5)) * 2048 + col] = f2b(v);
            }
}

// ---------------------------------------------------------------------------
// K3 (per step): attention for one n per block, 256 thr. A[n] staged in LDS
// once, reused for scores and weighted sum. Writes attn bf16 -> hx[512:1024].
__global__ __launch_bounds__(256) void attn_step_kernel(
    u16* __restrict__ hx, const u16* __restrict__ Ab)
{
    const int n = blockIdx.x, tid = threadIdx.x;
    __shared__ u16 As[16 * 520];          // A[n], row stride 520
    __shared__ u16 hsm[512];
    __shared__ float sred[16][17];
    __shared__ float wts[16];

    const u16* an = Ab + (size_t)n * 8192;
#pragma unroll
    for (int i = 0; i < 8; i++) {
        int fid = tid + i * 256;          // 2048 ushort4
        int p = fid >> 7, c4 = fid & 127;
        *(ushort4*)&As[p * 520 + c4 * 4] = *(const ushort4*)(an + p * 512 + c4 * 4);
    }
    if (tid < 128)
        *(ushort4*)&hsm[tid * 4] = *(const ushort4*)(hx + (size_t)n * 1024 + tid * 4);
    __syncthreads();

    {   // scores: thread (p = tid&15, chunk = tid>>4 of 32 elems)
        const int p = tid & 15, ch = tid >> 4;
        const u16* ap = &As[p * 520 + ch * 32];
        const u16* hp = &hsm[ch * 32];
        float s = 0.f;
#pragma unroll
        for (int j = 0; j < 32; j += 4) {
            ushort4 a4 = *(const ushort4*)(ap + j);
            ushort4 h4 = *(const ushort4*)(hp + j);
            s += b2f(a4.x)*b2f(h4.x) + b2f(a4.y)*b2f(h4.y)
               + b2f(a4.z)*b2f(h4.z) + b2f(a4.w)*b2f(h4.w);
        }
        sred[p][ch] = s;
    }
    __syncthreads();
    if (tid < 16) {
        float s = 0.f;
#pragma unroll
        for (int c2 = 0; c2 < 16; c2++) s += sred[tid][c2];
        s *= 0.04419417382415922f;        // 1/sqrt(512)
        float m = s;
#pragma unroll
        for (int mask = 1; mask <= 8; mask <<= 1) m = fmaxf(m, __shfl_xor(m, mask, 64));
        float e = __expf(s - m);
        float su = e;
#pragma unroll
        for (int mask = 1; mask <= 8; mask <<= 1) su += __shfl_xor(su, mask, 64);
        wts[tid] = e / su;
    }
    __syncthreads();
    {   // weighted sum: thread -> 2 cols
        const int d = tid * 2;
        float a0 = 0.f, a1 = 0.f;
#pragma unroll
        for (int p = 0; p < 16; p++) {
            float wp = wts[p];
            unsigned pr = *(const unsigned*)&As[p * 520 + d];
            a0 += wp * b2f((u16)(pr & 0xffff));
            a1 += wp * b2f((u16)(pr >> 16));
        }
        unsigned o = ((unsigned)f2b(a1) << 16) | (unsigned)f2b(a0);
        *(unsigned*)(hx + (size_t)n * 1024 + 512 + d) = o;
    }
}

// ---------------------------------------------------------------------------
// K4 (per step, MFMA): gates + nonlin + c/h update. grid (16 rt, 32 ctl),
// 512 blocks (2/CU). Wave ty handles gate type ty for 16 rows x 16 h-cols,
// K=1024 from LDS A-tile; LDS combine; wave 0 epilogue.
__global__ __launch_bounds__(256) void gates_step_kernel(
    const u16* __restrict__ hx_in, const u16* __restrict__ what,
    const u16* __restrict__ xpt, float* __restrict__ c,
    u16* __restrict__ hx_out, u16* __restrict__ hallbt)
{
    const int rt = blockIdx.x, ctl = blockIdx.y;
    const int tid = threadIdx.x, ty = tid >> 6, lane = tid & 63;
    const int lm = lane & 15, lkq = lane >> 4, lk = lkq * 8;
    const int r0 = rt * 16, hcolb = ctl * 16;

    __shared__ u16 As[16 * 1032];         // 16 rows x 1024, pad 8 (33 KB)
    __shared__ float gred[3][64][4];      // gate types 1..3

#pragma unroll
    for (int i = 0; i < 16; i++) {
        int fid = tid + i * 256;          // 4096 ushort4
        int r = fid >> 8, c4 = fid & 255;
        *(ushort4*)&As[r * 1032 + c4 * 4] =
            *(const ushort4*)(hx_in + (size_t)(r0 + r) * 1024 + c4 * 4);
    }
    __syncthreads();

    f32x4 acc = (f32x4){0.f, 0.f, 0.f, 0.f};
    const u16* brow = what + (size_t)(ty * 512 + hcolb + lm) * 1024 + lk;
    const u16* arow = &As[lm * 1032 + lk];
    for (int kc = 0; kc < 1024; kc += 32) {
        bf16x8 af = *(const bf16x8*)(arow + kc);
        bf16x8 bfg = *(const bf16x8*)(brow + kc);
        acc = __builtin_amdgcn_mfma_f32_16x16x32_bf16(af, bfg, acc, 0, 0, 0);
    }
    if (ty > 0) {
#pragma unroll
        for (int r = 0; r < 4; r++) gred[ty - 1][lane][r] = acc[r];
    }
    __syncthreads();
    if (ty == 0) {
#pragma unroll
        for (int r = 0; r < 4; r++) {
            const int n = r0 + lkq * 4 + r;
            const int hcol = hcolb + lm;
            const u16* xq = xpt + (size_t)n * 2048;
            float ai  = acc[r]            + b2f(xq[hcol]);
            float af_ = gred[0][lane][r]  + b2f(xq[512 + hcol]);
            float ao  = gred[1][lane][r]  + b2f(xq[1024 + hcol]);
            float ag  = gred[2][lane][r]  + b2f(xq[1536 + hcol]);
            float ig = 1.f / (1.f + __expf(-ai));
            float fg = 1.f / (1.f + __expf(-af_));
            float og = 1.f / (1.f + __expf(-ao));
            float gv = tanhf(ag);
            const int idx = n * 512 + hcol;
            float cn = fg * c[idx] + ig * gv;
            float hn = og * tanhf(cn);
            c[idx] = cn;
            u16 hb = f2b(hn);
            hx_out[(size_t)n * 1024 + hcol] = hb;
            hallbt[idx] = hb;
        }
    }
}

// ---------------------------------------------------------------------------
// K5 (MFMA): vocab scores + fused logsumexp partials + target extract.
// (reverted to Round-5 measured-good config: 20 vt x 128 rt, 4x8 tile)
__global__ __launch_bounds__(256) void vocab_mfma_kernel(
    const u16* __restrict__ hallb, const u16* __restrict__ Wvt,
    const float* __restrict__ bv, const int* __restrict__ caps,
    float* __restrict__ pmax, float* __restrict__ psum, float* __restrict__ tgt)
{
    const int vt = blockIdx.x, rt = blockIdx.y;
    const int tid = threadIdx.x, w = tid >> 6, lane = tid & 63;
    const int r0 = rt * 64;
    const int lm = lane & 15, lkq = lane >> 4, lk = lkq * 8;
    const int nbase = vt * 512 + w * 128;

    __shared__ int tvs[64];
    __shared__ float cm[64][4], cs[64][4];
    if (tid < 64) {
        int row = r0 + tid;                              // row = t*256 + n
        tvs[tid] = caps[(row & 255) * 33 + (row >> 8) + 1];
    }

    f32x4 acc[4][8];
#pragma unroll
    for (int mt = 0; mt < 4; mt++)
#pragma unroll
        for (int nt = 0; nt < 8; nt++) acc[mt][nt] = (f32x4){0.f, 0.f, 0.f, 0.f};

    for (int kc = 0; kc < 512; kc += 32) {
        bf16x8 af[4];
#pragma unroll
        for (int mt = 0; mt < 4; mt++)
            af[mt] = *(const bf16x8*)(hallb + (size_t)(r0 + mt * 16 + lm) * 512 + kc + lk);
#pragma unroll
        for (int nt = 0; nt < 8; nt++) {
            bf16x8 bfg = *(const bf16x8*)(Wvt + (size_t)(nbase + nt * 16 + lm) * 512 + kc + lk);
#pragma unroll
            for (int mt = 0; mt < 4; mt++)
                acc[mt][nt] = __builtin_amdgcn_mfma_f32_16x16x32_bf16(af[mt], bfg, acc[mt][nt], 0, 0, 0);
        }
    }
    __syncthreads();

    float bvv[8]; bool vld[8];
#pragma unroll
    for (int nt = 0; nt < 8; nt++) {
        int col = nbase + nt * 16 + lm;
        vld[nt] = (col < NV);
        bvv[nt] = vld[nt] ? bv[col] : 0.f;
    }
#pragma unroll
    for (int mt = 0; mt < 4; mt++)
#pragma unroll
        for (int r = 0; r < 4; r++) {
            int rloc = mt * 16 + lkq * 4 + r;
            int row = r0 + rloc;
            int tv = tvs[rloc];
            float vals[8]; float m = -1e30f;
#pragma unroll
            for (int nt = 0; nt < 8; nt++) {
                int col = nbase + nt * 16 + lm;
                float v = vld[nt] ? (acc[mt][nt][r] + bvv[nt]) : -1e30f;
                vals[nt] = v;
                m = fmaxf(m, v);
                if (col == tv) tgt[row] = v;
            }
#pragma unroll
            for (int mask = 1; mask <= 8; mask <<= 1) m = fmaxf(m, __shfl_xor(m, mask, 64));
            float s = 0.f;
#pragma unroll
            for (int nt = 0; nt < 8; nt++) s += __expf(vals[nt] - m);
#pragma unroll
            for (int mask = 1; mask <= 8; mask <<= 1) s += __shfl_xor(s, mask, 64);
            if (lm == 0) { cm[rloc][w] = m; cs[rloc][w] = s; }
        }
    __syncthreads();
    if (tid < 64) {
        int row = r0 + tid;
        float M = fmaxf(fmaxf(cm[tid][0], cm[tid][1]), fmaxf(cm[tid][2], cm[tid][3]));
        float S = cs[tid][0] * __expf(cm[tid][0] - M) + cs[tid][1] * __expf(cm[tid][1] - M)
                + cs[tid][2] * __expf(cm[tid][2] - M) + cs[tid][3] * __expf(cm[tid][3] - M);
        pmax[row * VT_N + vt] = M;
        psum[row * VT_N + vt] = S;
    }
}

// ---------------------------------------------------------------------------
__global__ __launch_bounds__(256) void loss_reduce_kernel(
    const float* __restrict__ pmax, const float* __restrict__ psum,
    const float* __restrict__ tgt, const int* __restrict__ caps,
    float* __restrict__ loss)
{
    const int row = blockIdx.x * 256 + threadIdx.x;
    float nll = 0.f;
    const int t = row >> 8, n = row & 255;
    const int tv = caps[n * 33 + t + 1];
    if (tv != 0) {
        float M = -1e30f;
#pragma unroll
        for (int vt = 0; vt < VT_N; vt++) M = fmaxf(M, pmax[row * VT_N + vt]);
        float S = 0.f;
#pragma unroll
        for (int vt = 0; vt < VT_N; vt++) S += psum[row * VT_N + vt] * __expf(pmax[row * VT_N + vt] - M);
        nll = logf(S) + M - tgt[row];
    }
#pragma unroll
    for (int off = 32; off; off >>= 1) nll += __shfl_down(nll, off, 64);
    __shared__ float r4[4];
    if ((threadIdx.x & 63) == 0) r4[threadIdx.x >> 6] = nll;
    __syncthreads();
    if (threadIdx.x == 0)
        atomicAdd(loss, (r4[0] + r4[1] + r4[2] + r4[3]) * (1.f / 256.f));
}

__global__ void finalize_kernel(const float* __restrict__ loss, float* __restrict__ out)
{
    if (threadIdx.x == 0 && blockIdx.x == 0) out[0] = loss[0];
}

// ---------------------------------------------------------------------------
extern "C" void kernel_launch(void* const* d_in, const int* in_sizes, int n_in,
                              void* d_out, int out_size, void* d_ws, size_t ws_size,
                              hipStream_t stream) {
    const float* feats = (const float*)d_in[0];
    const int*   caps  = (const int*)d_in[1];
    const float* Wp    = (const float*)d_in[2];
    const float* bp    = (const float*)d_in[3];
    const float* We    = (const float*)d_in[4];
    const float* Wx    = (const float*)d_in[5];
    const float* Wh    = (const float*)d_in[6];
    const float* Wattn = (const float*)d_in[7];
    const float* bb    = (const float*)d_in[8];
    const float* Wv    = (const float*)d_in[9];
    const float* bv    = (const float*)d_in[10];

    char* ws = (char*)d_ws;
    float* c     = (float*)(ws + B_C);
    float* pmax  = (float*)(ws + B_PMAX);
    float* psum  = (float*)(ws + B_PSUM);
    float* tgt   = (float*)(ws + B_TGT);
    float* loss  = (float*)(ws + B_LOSS);
    u16*   Ab    = (u16*)(ws + B_AB);
    u16*   xpb   = (u16*)(ws + B_XPB);
    u16*   hallb = (u16*)(ws + B_HALLB);
    u16*   wvt   = (u16*)(ws + B_WVT);
    u16*   wxt   = (u16*)(ws + B_WXT);
    u16*   what  = (u16*)(ws + B_WHAT);
    u16*   hx[2] = { (u16*)(ws + B_HX0), (u16*)(ws + B_HX1) };

    hipMemsetAsync(loss, 0, sizeof(float), stream);

    tconv_kernel<<<dim3(160, 8), 256, 0, stream>>>(Wv, wvt, 512, NV, NVP, 512, 0);
    tconv_kernel<<<dim3(32, 4),  256, 0, stream>>>(Wx, wxt, 256, 2048, 2048, 256, 0);
    tconv_kernel<<<dim3(32, 8),  256, 0, stream>>>(Wh, what, 512, 2048, 2048, 1024, 0);
    tconv_kernel<<<dim3(32, 8),  256, 0, stream>>>(Wattn, what, 512, 2048, 2048, 1024, 512);
    proj_kernel<<<256, 256, 0, stream>>>(feats, Wp, bp, Ab, c, hx[0]);
    xp_mfma_kernel<<<dim3(4, 128), 256, 0, stream>>>(caps, We, wxt, bb, xpb);

    for (int t = 0; t < NT; t++) {
        const int in = t & 1, out = 1 - in;
        attn_step_kernel<<<256, 256, 0, stream>>>(hx[in], Ab);
        gates_step_kernel<<<dim3(16, 32), 256, 0, stream>>>(
            hx[in], what, xpb + (size_t)t * 524288, c,
            hx[out], hallb + (size_t)t * 131072);
    }

    vocab_mfma_kernel<<<dim3(VT_N, 128), 256, 0, stream>>>(
        hallb, wvt, bv, caps, pmax, psum, tgt);
    loss_reduce_kernel<<<32, 256, 0, stream>>>(pmax, psum, tgt, caps, loss);
    finalize_kernel<<<1, 64, 0, stream>>>(loss, (float*)d_out);
}

// Round 9
// 1228.372 us; speedup vs baseline: 3.6929x; 1.0359x over previous
//
#include <hip/hip_runtime.h>
#include <hip/hip_bf16.h>

#define NB   256
#define NT   32
#define NV   10000
#define NVP  10240
#define NDF  1280
#define NH   512
#define VT_N 20      // vocab col tiles of 512

typedef short bf16x8 __attribute__((ext_vector_type(8)));
typedef float f32x4  __attribute__((ext_vector_type(4)));
typedef unsigned short u16;

__device__ __forceinline__ float b2f(u16 u) {
    union { unsigned i; float f; } v; v.i = ((unsigned)u) << 16; return v.f;
}
__device__ __forceinline__ u16 f2b(float f) {
    union { float f; unsigned i; } v; v.f = f;
    unsigned r = v.i + 0x7FFF + ((v.i >> 16) & 1);   // RNE
    return (u16)(r >> 16);
}

// ---------------- workspace layout (byte offsets, 16-aligned) --------------
static const size_t B_C     = 0;                                  // [256][512] f32 cell
static const size_t B_SCP   = B_C     + (size_t)256*512*4;        // [2][32][256][16] f32 score partials
static const size_t B_PMAX  = B_SCP   + (size_t)2*32*256*16*4;    // [8192][20] f32
static const size_t B_PSUM  = B_PMAX  + (size_t)8192*VT_N*4;      // [8192][20] f32
static const size_t B_TGT   = B_PSUM  + (size_t)8192*VT_N*4;      // [8192] f32
static const size_t B_LOSS  = B_TGT   + (size_t)8192*4;           // [1] f32
static const size_t B_AB    = B_LOSS  + 16;                       // [256][16][512] bf16
static const size_t B_XPB   = B_AB    + (size_t)256*16*512*2;     // [32][256][2048] bf16
static const size_t B_HALLB = B_XPB   + (size_t)32*256*2048*2;    // [32][256][512] bf16
static const size_t B_WVT   = B_HALLB + (size_t)32*256*512*2;     // [10240][512] bf16
static const size_t B_WXT   = B_WVT   + (size_t)10240*512*2;      // [2048][256] bf16
static const size_t B_WHAT  = B_WXT   + (size_t)2048*256*2;       // [2048][1024] bf16 (WhT|WattnT)
static const size_t B_HB0   = B_WHAT  + (size_t)2048*1024*2;      // [256][512] bf16 h ping
static const size_t B_HB1   = B_HB0   + (size_t)256*512*2;        // [256][512] bf16 h pong
static const size_t B_PREAW = B_HB1   + (size_t)256*512*2;        // [16*256][2048] bf16 (p*256+n)
// total ~82 MB

// ---------------------------------------------------------------------------
// T0: transpose+convert: src f32 [K][N] -> dst bf16 [Npad][ldK] at koff.
__global__ __launch_bounds__(256) void tconv_kernel(
    const float* __restrict__ src, u16* __restrict__ dst,
    int K, int N, int Npad, int ldK, int koff)
{
    __shared__ u16 tile[64][65];
    const int k0 = blockIdx.y * 64, n0 = blockIdx.x * 64, tid = threadIdx.x;
#pragma unroll
    for (int i = 0; i < 16; i++) {
        int idx = tid + i * 256;
        int kk = idx >> 6, nn = idx & 63;
        int n = n0 + nn;
        float v = (n < N) ? src[(size_t)(k0 + kk) * N + n] : 0.f;
        tile[kk][nn] = f2b(v);
    }
    __syncthreads();
#pragma unroll
    for (int i = 0; i < 16; i++) {
        int idx = tid + i * 256;
        int nn = idx >> 6, kk = idx & 63;
        int n = n0 + nn;
        if (n < Npad) dst[(size_t)n * ldK + koff + k0 + kk] = tile[kk][nn];
    }
}

// ---------------------------------------------------------------------------
// K1: A = feats.Wp + bp (bf16), c0 = mean_p A (f32); h0 bf16 -> hb0
__global__ __launch_bounds__(256) void proj_kernel(
    const float* __restrict__ feats, const float* __restrict__ Wp,
    const float* __restrict__ bp, u16* __restrict__ Ab,
    float* __restrict__ c0, u16* __restrict__ hb0)
{
    const int n = blockIdx.x, tid = threadIdx.x;
    __shared__ float fl[64][16];
    float acc0[16], acc1[16];
#pragma unroll
    for (int p = 0; p < 16; p++) { acc0[p] = 0.f; acc1[p] = 0.f; }
    const float* fn = feats + (size_t)n * (NDF * 16);
    const int l = tid * 4, cc = l >> 4, ij = l & 15;
    for (int c0i = 0; c0i < NDF; c0i += 64) {
        __syncthreads();
        float4 v = *(const float4*)(fn + (c0i + cc) * 16 + ij);
        fl[cc][ij] = v.x; fl[cc][ij+1] = v.y; fl[cc][ij+2] = v.z; fl[cc][ij+3] = v.w;
        __syncthreads();
        for (int c2 = 0; c2 < 64; c2++) {
            float w0 = Wp[(size_t)(c0i + c2) * NH + tid];
            float w1 = Wp[(size_t)(c0i + c2) * NH + tid + 256];
#pragma unroll
            for (int p = 0; p < 16; p++) {
                float f = fl[c2][p];
                acc0[p] += f * w0;
                acc1[p] += f * w1;
            }
        }
    }
    float bp0 = bp[tid], bp1 = bp[tid + 256];
    float s0 = 0.f, s1 = 0.f;
#pragma unroll
    for (int p = 0; p < 16; p++) {
        float a0 = acc0[p] + bp0, a1 = acc1[p] + bp1;
        Ab[(size_t)n * 8192 + p * 512 + tid]       = f2b(a0);
        Ab[(size_t)n * 8192 + p * 512 + tid + 256] = f2b(a1);
        s0 += a0; s1 += a1;
    }
    s0 *= 0.0625f; s1 *= 0.0625f;
    c0[n * 512 + tid] = s0;  c0[n * 512 + tid + 256] = s1;
    hb0[(size_t)n * 512 + tid]       = f2b(s0);
    hb0[(size_t)n * 512 + tid + 256] = f2b(s1);
}

// ---------------------------------------------------------------------------
// K2 (MFMA): xpb = embed@Wx + b  (bf16), rows stored as [t][n]
__global__ __launch_bounds__(256) void xp_mfma_kernel(
    const int* __restrict__ caps, const float* __restrict__ We,
    const u16* __restrict__ Wxt, const float* __restrict__ bb,
    u16* __restrict__ xpb)
{
    const int ct = blockIdx.x, rt = blockIdx.y;
    const int tid = threadIdx.x, w = tid >> 6, lane = tid & 63;
    const int r0 = rt * 64;
    const int lm = lane & 15, lkq = lane >> 4, lk = lkq * 8;
    const int nbase = ct * 512 + w * 128;

    int capm[4];
#pragma unroll
    for (int mt = 0; mt < 4; mt++) {
        int row = r0 + mt * 16 + lm;
        capm[mt] = caps[(row >> 5) * 33 + (row & 31)];
    }
    f32x4 acc[4][8];
#pragma unroll
    for (int mt = 0; mt < 4; mt++)
#pragma unroll
        for (int nt = 0; nt < 8; nt++) acc[mt][nt] = (f32x4){0.f, 0.f, 0.f, 0.f};

    for (int kc = 0; kc < 256; kc += 32) {
        bf16x8 af[4];
#pragma unroll
        for (int mt = 0; mt < 4; mt++) {
            const float* ap = We + (size_t)capm[mt] * 256 + kc + lk;
            float4 f0 = *(const float4*)ap;
            float4 f1 = *(const float4*)(ap + 4);
            bf16x8 t;
            t[0] = (short)f2b(f0.x); t[1] = (short)f2b(f0.y);
            t[2] = (short)f2b(f0.z); t[3] = (short)f2b(f0.w);
            t[4] = (short)f2b(f1.x); t[5] = (short)f2b(f1.y);
            t[6] = (short)f2b(f1.z); t[7] = (short)f2b(f1.w);
            af[mt] = t;
        }
#pragma unroll
        for (int nt = 0; nt < 8; nt++) {
            bf16x8 bfg = *(const bf16x8*)(Wxt + (size_t)(nbase + nt * 16 + lm) * 256 + kc + lk);
#pragma unroll
            for (int mt = 0; mt < 4; mt++)
                acc[mt][nt] = __builtin_amdgcn_mfma_f32_16x16x32_bf16(af[mt], bfg, acc[mt][nt], 0, 0, 0);
        }
    }
    float bbv[8];
#pragma unroll
    for (int nt = 0; nt < 8; nt++) bbv[nt] = bb[nbase + nt * 16 + lm];
#pragma unroll
    for (int mt = 0; mt < 4; mt++)
#pragma unroll
        for (int nt = 0; nt < 8; nt++)
#pragma unroll
            for (int r = 0; r < 4; r++) {
                int row = r0 + mt * 16 + lkq * 4 + r;   // row = n*32 + t
                int col = nbase + nt * 16 + lm;
                float v = acc[mt][nt][r] + bbv[nt];
                xpb[((size_t)(row & 31) * 256 + (row >> 5)) * 2048 + col] = f2b(v);
            }
}

// ---------------------------------------------------------------------------
// K3 (MFMA, once): PreAW[p*256+n][col] = A[n,p,:] @ Wattn  (bf16 out)
// grid (4 ct of 512 cols, 64 rt of 64 rows), 256 thr = 4 waves.
__global__ __launch_bounds__(256) void preaw_mfma_kernel(
    const u16* __restrict__ Ab, const u16* __restrict__ what,
    u16* __restrict__ preaw)
{
    const int ct = blockIdx.x, rt = blockIdx.y;
    const int tid = threadIdx.x, w = tid >> 6, lane = tid & 63;
    const int r0 = rt * 64;
    const int lm = lane & 15, lkq = lane >> 4, lk = lkq * 8;
    const int nbase = ct * 512 + w * 128;

    f32x4 acc[4][8];
#pragma unroll
    for (int mt = 0; mt < 4; mt++)
#pragma unroll
        for (int nt = 0; nt < 8; nt++) acc[mt][nt] = (f32x4){0.f, 0.f, 0.f, 0.f};

    for (int kc = 0; kc < 512; kc += 32) {
        bf16x8 af[4];
#pragma unroll
        for (int mt = 0; mt < 4; mt++) {
            int row = r0 + mt * 16 + lm;                  // row = p*256+n
            af[mt] = *(const bf16x8*)(Ab + ((size_t)(row & 255) * 16 + (row >> 8)) * 512 + kc + lk);
        }
#pragma unroll
        for (int nt = 0; nt < 8; nt++) {
            bf16x8 bfg = *(const bf16x8*)(what + (size_t)(nbase + nt * 16 + lm) * 1024 + 512 + kc + lk);
#pragma unroll
            for (int mt = 0; mt < 4; mt++)
                acc[mt][nt] = __builtin_amdgcn_mfma_f32_16x16x32_bf16(af[mt], bfg, acc[mt][nt], 0, 0, 0);
        }
    }
#pragma unroll
    for (int mt = 0; mt < 4; mt++)
#pragma unroll
        for (int nt = 0; nt < 8; nt++)
#pragma unroll
            for (int r = 0; r < 4; r++) {
                int row = r0 + mt * 16 + lkq * 4 + r;
                int col = nbase + nt * 16 + lm;
                preaw[(size_t)row * 2048 + col] = f2b(acc[mt][nt][r]);
            }
}

// ---------------------------------------------------------------------------
// K4 (once): scores for t=0 from h0: scp[cg=0][n][p] = h0[n]·A[n,p]; zero cg>0
__global__ __launch_bounds__(64) void score_init_kernel(
    const u16* __restrict__ hb0, const u16* __restrict__ Ab,
    float* __restrict__ scp)
{
    const int n = blockIdx.x, lane = threadIdx.x;
    const u16* hp = hb0 + (size_t)n * 512 + lane * 8;
    ushort4 h0 = *(const ushort4*)hp, h1 = *(const ushort4*)(hp + 4);
    float hv0 = b2f(h0.x), hv1 = b2f(h0.y), hv2 = b2f(h0.z), hv3 = b2f(h0.w);
    float hv4 = b2f(h1.x), hv5 = b2f(h1.y), hv6 = b2f(h1.z), hv7 = b2f(h1.w);
    float mine = 0.f;
#pragma unroll
    for (int p = 0; p < 16; p++) {
        const u16* ap = Ab + (size_t)n * 8192 + p * 512 + lane * 8;
        ushort4 a0 = *(const ushort4*)ap, a1 = *(const ushort4*)(ap + 4);
        float s = hv0*b2f(a0.x) + hv1*b2f(a0.y) + hv2*b2f(a0.z) + hv3*b2f(a0.w)
                + hv4*b2f(a1.x) + hv5*b2f(a1.y) + hv6*b2f(a1.z) + hv7*b2f(a1.w);
#pragma unroll
        for (int mask = 1; mask <= 32; mask <<= 1) s += __shfl_xor(s, mask, 64);
        if (lane == p) mine = s;
    }
    if (lane < 16) scp[n * 16 + lane] = mine;
    for (int i = lane; i < 31 * 16; i += 64)
        scp[(1 + (i >> 4)) * 4096 + n * 16 + (i & 15)] = 0.f;
}

// ---------------------------------------------------------------------------
// K5 (per step, single kernel): softmax(scores) -> gates MFMA (K=512, h@Wh)
// + Sum_p wts*PreAW + xp -> nonlin -> c,h update -> score partials for t+1.
// grid (16 rt, 32 cg) = 512 blocks (2/CU), 256 thr = 4 waves (wave = gate type).
__global__ __launch_bounds__(256) void gates_fused_kernel(
    const u16* __restrict__ hb_in, const float* __restrict__ scp_in,
    const u16* __restrict__ what, const u16* __restrict__ preaw,
    const u16* __restrict__ xpt, const u16* __restrict__ Ab,
    float* __restrict__ c, u16* __restrict__ hb_out,
    u16* __restrict__ hallbt, float* __restrict__ scp_out)
{
    const int rt = blockIdx.x, cg = blockIdx.y;
    const int tid = threadIdx.x, ty = tid >> 6, lane = tid & 63;
    const int lm = lane & 15, lkq = lane >> 4, lk = lkq * 8;
    const int r0 = rt * 16, hc0 = cg * 16;

    __shared__ u16 hs[16 * 520];
    __shared__ float sred[16][17];
    __shared__ float wts[16][17];
    __shared__ float gred[3][64][4];
    __shared__ u16 hnew[16][16];

    // stage h rows (independent of score path)
#pragma unroll
    for (int i = 0; i < 8; i++) {
        int fid = tid + i * 256;          // 2048 ushort4
        int r = fid >> 7, c4 = fid & 127;
        *(ushort4*)&hs[r * 520 + c4 * 4] =
            *(const ushort4*)(hb_in + (size_t)(r0 + r) * 512 + c4 * 4);
    }
    // sum score partials: thread (r = tid>>4, p = tid&15)
    {
        const int r = tid >> 4, p = tid & 15;
        float s = 0.f;
#pragma unroll
        for (int g = 0; g < 32; g++) s += scp_in[g * 4096 + (r0 + r) * 16 + p];
        sred[r][p] = s * 0.04419417382415922f;   // 1/sqrt(512)
    }
    __syncthreads();
    {   // softmax (redundant per thread over its row; LDS broadcast reads)
        const int r = tid >> 4, p = tid & 15;
        float m = -1e30f;
#pragma unroll
        for (int q = 0; q < 16; q++) m = fmaxf(m, sred[r][q]);
        float su = 0.f;
#pragma unroll
        for (int q = 0; q < 16; q++) su += __expf(sred[r][q] - m);
        wts[r][p] = __expf(sred[r][p] - m) / su;
    }
    __syncthreads();

    // MFMA: h(16x512) @ WhT-slice -> (16 rows x 16 cols of gate type ty)
    f32x4 acc = (f32x4){0.f, 0.f, 0.f, 0.f};
    const u16* brow = what + (size_t)(ty * 512 + hc0 + lm) * 1024 + lk;
    const u16* arow = &hs[lm * 520 + lk];
    for (int kc = 0; kc < 512; kc += 32) {
        bf16x8 af = *(const bf16x8*)(arow + kc);
        bf16x8 bfg = *(const bf16x8*)(brow + kc);
        acc = __builtin_amdgcn_mfma_f32_16x16x32_bf16(af, bfg, acc, 0, 0, 0);
    }
    // + xp + attention contribution via PreAW
    float val[4];
#pragma unroll
    for (int r = 0; r < 4; r++) {
        const int rl = lkq * 4 + r, n = r0 + rl;
        const int col = ty * 512 + hc0 + lm;
        float s = acc[r] + b2f(xpt[(size_t)n * 2048 + col]);
#pragma unroll
        for (int p = 0; p < 16; p++)
            s += wts[rl][p] * b2f(preaw[((size_t)p * 256 + n) * 2048 + col]);
        val[r] = s;
    }
    if (ty > 0) {
#pragma unroll
        for (int r = 0; r < 4; r++) gred[ty - 1][lane][r] = val[r];
    }
    __syncthreads();
    if (ty == 0) {
#pragma unroll
        for (int r = 0; r < 4; r++) {
            const int rl = lkq * 4 + r, n = r0 + rl;
            const int hcol = hc0 + lm;
            float ai  = val[r];
            float af_ = gred[0][lane][r];
            float ao  = gred[1][lane][r];
            float ag  = gred[2][lane][r];
            float ig = 1.f / (1.f + __expf(-ai));
            float fg = 1.f / (1.f + __expf(-af_));
            float og = 1.f / (1.f + __expf(-ao));
            float gv = tanhf(ag);
            const int idx = n * 512 + hcol;
            float cn = fg * c[idx] + ig * gv;
            float hn = og * tanhf(cn);
            c[idx] = cn;
            u16 hbv = f2b(hn);
            hb_out[idx] = hbv;
            hallbt[idx] = hbv;
            hnew[rl][lm] = hbv;
        }
    }
    __syncthreads();
    // score partials for step t+1: thread (r,p): sum over this block's 16 hcols
    {
        const int r = tid >> 4, p = tid & 15, n = r0 + r;
        const u16* ap = Ab + (size_t)n * 8192 + p * 512 + hc0;
        float s = 0.f;
#pragma unroll
        for (int j = 0; j < 16; j++) s += b2f(hnew[r][j]) * b2f(ap[j]);
        scp_out[cg * 4096 + n * 16 + p] = s;
    }
}

// ---------------------------------------------------------------------------
// K6 (MFMA): vocab scores + fused logsumexp partials + target extract.
__global__ __launch_bounds__(256) void vocab_mfma_kernel(
    const u16* __restrict__ hallb, const u16* __restrict__ Wvt,
    const float* __restrict__ bv, const int* __restrict__ caps,
    float* __restrict__ pmax, float* __restrict__ psum, float* __restrict__ tgt)
{
    const int vt = blockIdx.x, rt = blockIdx.y;
    const int tid = threadIdx.x, w = tid >> 6, lane = tid & 63;
    const int r0 = rt * 64;
    const int lm = lane & 15, lkq = lane >> 4, lk = lkq * 8;
    const int nbase = vt * 512 + w * 128;

    __shared__ int tvs[64];
    __shared__ float cm[64][4], cs[64][4];
    if (tid < 64) {
        int row = r0 + tid;                              // row = t*256 + n
        tvs[tid] = caps[(row & 255) * 33 + (row >> 8) + 1];
    }

    f32x4 acc[4][8];
#pragma unroll
    for (int mt = 0; mt < 4; mt++)
#pragma unroll
        for (int nt = 0; nt < 8; nt++) acc[mt][nt] = (f32x4){0.f, 0.f, 0.f, 0.f};

    for (int kc = 0; kc < 512; kc += 32) {
        bf16x8 af[4];
#pragma unroll
        for (int mt = 0; mt < 4; mt++)
            af[mt] = *(const bf16x8*)(hallb + (size_t)(r0 + mt * 16 + lm) * 512 + kc + lk);
#pragma unroll
        for (int nt = 0; nt < 8; nt++) {
            bf16x8 bfg = *(const bf16x8*)(Wvt + (size_t)(nbase + nt * 16 + lm) * 512 + kc + lk);
#pragma unroll
            for (int mt = 0; mt < 4; mt++)
                acc[mt][nt] = __builtin_amdgcn_mfma_f32_16x16x32_bf16(af[mt], bfg, acc[mt][nt], 0, 0, 0);
        }
    }
    __syncthreads();

    float bvv[8]; bool vld[8];
#pragma unroll
    for (int nt = 0; nt < 8; nt++) {
        int col = nbase + nt * 16 + lm;
        vld[nt] = (col < NV);
        bvv[nt] = vld[nt] ? bv[col] : 0.f;
    }
#pragma unroll
    for (int mt = 0; mt < 4; mt++)
#pragma unroll
        for (int r = 0; r < 4; r++) {
            int rloc = mt * 16 + lkq * 4 + r;
            int row = r0 + rloc;
            int tv = tvs[rloc];
            float vals[8]; float m = -1e30f;
#pragma unroll
            for (int nt = 0; nt < 8; nt++) {
                int col = nbase + nt * 16 + lm;
                float v = vld[nt] ? (acc[mt][nt][r] + bvv[nt]) : -1e30f;
                vals[nt] = v;
                m = fmaxf(m, v);
                if (col == tv) tgt[row] = v;
            }
#pragma unroll
            for (int mask = 1; mask <= 8; mask <<= 1) m = fmaxf(m, __shfl_xor(m, mask, 64));
            float s = 0.f;
#pragma unroll
            for (int nt = 0; nt < 8; nt++) s += __expf(vals[nt] - m);
#pragma unroll
            for (int mask = 1; mask <= 8; mask <<= 1) s += __shfl_xor(s, mask, 64);
            if (lm == 0) { cm[rloc][w] = m; cs[rloc][w] = s; }
        }
    __syncthreads();
    if (tid < 64) {
        int row = r0 + tid;
        float M = fmaxf(fmaxf(cm[tid][0], cm[tid][1]), fmaxf(cm[tid][2], cm[tid][3]));
        float S = cs[tid][0] * __expf(cm[tid][0] - M) + cs[tid][1] * __expf(cm[tid][1] - M)
                + cs[tid][2] * __expf(cm[tid][2] - M) + cs[tid][3] * __expf(cm[tid][3] - M);
        pmax[row * VT_N + vt] = M;
        psum[row * VT_N + vt] = S;
    }
}

// ---------------------------------------------------------------------------
__global__ __launch_bounds__(256) void loss_reduce_kernel(
    const float* __restrict__ pmax, const float* __restrict__ psum,
    const float* __restrict__ tgt, const int* __restrict__ caps,
    float* __restrict__ loss)
{
    const int row = blockIdx.x * 256 + threadIdx.x;
    float nll = 0.f;
    const int t = row >> 8, n = row & 255;
    const int tv = caps[n * 33 + t + 1];
    if (tv != 0) {
        float M = -1e30f;
#pragma unroll
        for (int vt = 0; vt < VT_N; vt++) M = fmaxf(M, pmax[row * VT_N + vt]);
        float S = 0.f;
#pragma unroll
        for (int vt = 0; vt < VT_N; vt++) S += psum[row * VT_N + vt] * __expf(pmax[row * VT_N + vt] - M);
        nll = logf(S) + M - tgt[row];
    }
#pragma unroll
    for (int off = 32; off; off >>= 1) nll += __shfl_down(nll, off, 64);
    __shared__ float r4[4];
    if ((threadIdx.x & 63) == 0) r4[threadIdx.x >> 6] = nll;
    __syncthreads();
    if (threadIdx.x == 0)
        atomicAdd(loss, (r4[0] + r4[1] + r4[2] + r4[3]) * (1.f / 256.f));
}

__global__ void finalize_kernel(const float* __restrict__ loss, float* __restrict__ out)
{
    if (threadIdx.x == 0 && blockIdx.x == 0) out[0] = loss[0];
}

// ---------------------------------------------------------------------------
extern "C" void kernel_launch(void* const* d_in, const int* in_sizes, int n_in,
                              void* d_out, int out_size, void* d_ws, size_t ws_size,
                              hipStream_t stream) {
    const float* feats = (const float*)d_in[0];
    const int*   caps  = (const int*)d_in[1];
    const float* Wp    = (const float*)d_in[2];
    const float* bp    = (const float*)d_in[3];
    const float* We    = (const float*)d_in[4];
    const float* Wx    = (const float*)d_in[5];
    const float* Wh    = (const float*)d_in[6];
    const float* Wattn = (const float*)d_in[7];
    const float* bb    = (const float*)d_in[8];
    const float* Wv    = (const float*)d_in[9];
    const float* bv    = (const float*)d_in[10];

    char* ws = (char*)d_ws;
    float* c     = (float*)(ws + B_C);
    float* scp0  = (float*)(ws + B_SCP);
    float* scp1  = scp0 + (size_t)32 * 4096;
    float* pmax  = (float*)(ws + B_PMAX);
    float* psum  = (float*)(ws + B_PSUM);
    float* tgt   = (float*)(ws + B_TGT);
    float* loss  = (float*)(ws + B_LOSS);
    u16*   Ab    = (u16*)(ws + B_AB);
    u16*   xpb   = (u16*)(ws + B_XPB);
    u16*   hallb = (u16*)(ws + B_HALLB);
    u16*   wvt   = (u16*)(ws + B_WVT);
    u16*   wxt   = (u16*)(ws + B_WXT);
    u16*   what  = (u16*)(ws + B_WHAT);
    u16*   hb[2] = { (u16*)(ws + B_HB0), (u16*)(ws + B_HB1) };
    u16*   preaw = (u16*)(ws + B_PREAW);

    hipMemsetAsync(loss, 0, sizeof(float), stream);

    tconv_kernel<<<dim3(160, 8), 256, 0, stream>>>(Wv, wvt, 512, NV, NVP, 512, 0);
    tconv_kernel<<<dim3(32, 4),  256, 0, stream>>>(Wx, wxt, 256, 2048, 2048, 256, 0);
    tconv_kernel<<<dim3(32, 8),  256, 0, stream>>>(Wh, what, 512, 2048, 2048, 1024, 0);
    tconv_kernel<<<dim3(32, 8),  256, 0, stream>>>(Wattn, what, 512, 2048, 2048, 1024, 512);
    proj_kernel<<<256, 256, 0, stream>>>(feats, Wp, bp, Ab, c, hb[0]);
    xp_mfma_kernel<<<dim3(4, 128), 256, 0, stream>>>(caps, We, wxt, bb, xpb);
    preaw_mfma_kernel<<<dim3(4, 64), 256, 0, stream>>>(Ab, what, preaw);
    score_init_kernel<<<256, 64, 0, stream>>>(hb[0], Ab, scp0);

    for (int t = 0; t < NT; t++) {
        const int in = t & 1;
        gates_fused_kernel<<<dim3(16, 32), 256, 0, stream>>>(
            hb[in], in ? scp1 : scp0, what, preaw,
            xpb + (size_t)t * 524288, Ab, c,
            hb[1 - in], hallb + (size_t)t * 131072,
            in ? scp0 : scp1);
    }

    vocab_mfma_kernel<<<dim3(VT_N, 128), 256, 0, stream>>>(
        hallb, wvt, bv, caps, pmax, psum, tgt);
    loss_reduce_kernel<<<32, 256, 0, stream>>>(pmax, psum, tgt, caps, loss);
    finalize_kernel<<<1, 64, 0, stream>>>(loss, (float*)d_out);
}

// Round 10
// 976.649 us; speedup vs baseline: 4.6447x; 1.2577x over previous
//
#include <hip/hip_runtime.h>
#include <hip/hip_bf16.h>

#define NB   256
#define NT   32
#define NV   10000
#define NVP  10240
#define NDF  1280
#define NH   512
#define VT_N 20      // vocab col tiles of 512

typedef short bf16x8 __attribute__((ext_vector_type(8)));
typedef float f32x4  __attribute__((ext_vector_type(4)));
typedef unsigned short u16;

__device__ __forceinline__ float b2f(u16 u) {
    union { unsigned i; float f; } v; v.i = ((unsigned)u) << 16; return v.f;
}
__device__ __forceinline__ u16 f2b(float f) {
    union { float f; unsigned i; } v; v.f = f;
    unsigned r = v.i + 0x7FFF + ((v.i >> 16) & 1);   // RNE
    return (u16)(r >> 16);
}

// ---------------- workspace layout (byte offsets, 16-aligned) --------------
static const size_t B_C     = 0;                                  // [256][512] f32 cell
static const size_t B_SCP   = B_C     + (size_t)256*512*4;        // [2][32][256][16] f32
static const size_t B_PMAX  = B_SCP   + (size_t)2*32*256*16*4;    // [8192][20] f32
static const size_t B_PSUM  = B_PMAX  + (size_t)8192*VT_N*4;      // [8192][20] f32
static const size_t B_TGT   = B_PSUM  + (size_t)8192*VT_N*4;      // [8192] f32
static const size_t B_LOSS  = B_TGT   + (size_t)8192*4;           // [1] f32
static const size_t B_AB    = B_LOSS  + 16;                       // [256][16][512] bf16
static const size_t B_XPB   = B_AB    + (size_t)256*16*512*2;     // [32][256][2048] bf16
static const size_t B_HALLB = B_XPB   + (size_t)32*256*2048*2;    // [32][256][512] bf16
static const size_t B_WVT   = B_HALLB + (size_t)32*256*512*2;     // [10240][512] bf16
static const size_t B_WXT   = B_WVT   + (size_t)10240*512*2;      // [2048][256] bf16
static const size_t B_WHAT  = B_WXT   + (size_t)2048*256*2;       // [2048][1024] bf16
static const size_t B_HB0   = B_WHAT  + (size_t)2048*1024*2;      // [256][512] bf16 h ping
static const size_t B_HB1   = B_HB0   + (size_t)256*512*2;        // [256][512] bf16 h pong
static const size_t B_PREAW = B_HB1   + (size_t)256*512*2;        // [16*256][2048] bf16
// Aliases (prep-only, dead before overwriter runs):
//   fT  (4096x1280 bf16 = 10.49 MB) lives at B_WVT  (wvt written later)
//   WpT (512x1280 bf16 = 1.31 MB)   lives at B_XPB  (xpb written later)

// ---------------------------------------------------------------------------
// T0: transpose+convert: src f32 [K][N] -> dst bf16 [Npad][ldK] at koff.
__global__ __launch_bounds__(256) void tconv_kernel(
    const float* __restrict__ src, u16* __restrict__ dst,
    int K, int N, int Npad, int ldK, int koff)
{
    __shared__ u16 tile[64][65];
    const int k0 = blockIdx.y * 64, n0 = blockIdx.x * 64, tid = threadIdx.x;
#pragma unroll
    for (int i = 0; i < 16; i++) {
        int idx = tid + i * 256;
        int kk = idx >> 6, nn = idx & 63;
        int n = n0 + nn;
        float v = (n < N) ? src[(size_t)(k0 + kk) * N + n] : 0.f;
        tile[kk][nn] = f2b(v);
    }
    __syncthreads();
#pragma unroll
    for (int i = 0; i < 16; i++) {
        int idx = tid + i * 256;
        int nn = idx >> 6, kk = idx & 63;
        int n = n0 + nn;
        if (n < Npad) dst[(size_t)n * ldK + koff + k0 + kk] = tile[kk][nn];
    }
}

// ---------------------------------------------------------------------------
// P1: feats f32 [n][c][p16] -> fT bf16 [n*16+p][1280]. grid (20 cch, 256 n).
__global__ __launch_bounds__(256) void ftrans_kernel(
    const float* __restrict__ feats, u16* __restrict__ fT)
{
    const int cch = blockIdx.x, n = blockIdx.y, tid = threadIdx.x;
    __shared__ u16 lt[64][17];
    const int c0 = cch * 64;
    const int c = tid >> 2, p4 = (tid & 3) * 4;
    float4 v = *(const float4*)(feats + (size_t)n * 20480 + (size_t)(c0 + c) * 16 + p4);
    lt[c][p4] = f2b(v.x); lt[c][p4 + 1] = f2b(v.y);
    lt[c][p4 + 2] = f2b(v.z); lt[c][p4 + 3] = f2b(v.w);
    __syncthreads();
    const int p = tid >> 4, cg = tid & 15;
    ushort4 o;
    o.x = lt[cg * 4 + 0][p]; o.y = lt[cg * 4 + 1][p];
    o.z = lt[cg * 4 + 2][p]; o.w = lt[cg * 4 + 3][p];
    *(ushort4*)(fT + (size_t)(n * 16 + p) * 1280 + c0 + cg * 4) = o;
}

// ---------------------------------------------------------------------------
// P2 (MFMA): Ab[row][col] = fT[row] @ WpT^T + bp, row = n*16+p. grid 64 rt.
__global__ __launch_bounds__(256) void proj_gemm_kernel(
    const u16* __restrict__ fT, const u16* __restrict__ WpT,
    const float* __restrict__ bp, u16* __restrict__ Ab)
{
    const int rt = blockIdx.x;
    const int tid = threadIdx.x, w = tid >> 6, lane = tid & 63;
    const int r0 = rt * 64;
    const int lm = lane & 15, lkq = lane >> 4, lk = lkq * 8;
    const int nbase = w * 128;

    f32x4 acc[4][8];
#pragma unroll
    for (int mt = 0; mt < 4; mt++)
#pragma unroll
        for (int nt = 0; nt < 8; nt++) acc[mt][nt] = (f32x4){0.f, 0.f, 0.f, 0.f};

    for (int kc = 0; kc < 1280; kc += 32) {
        bf16x8 af[4];
#pragma unroll
        for (int mt = 0; mt < 4; mt++)
            af[mt] = *(const bf16x8*)(fT + (size_t)(r0 + mt * 16 + lm) * 1280 + kc + lk);
#pragma unroll
        for (int nt = 0; nt < 8; nt++) {
            bf16x8 bfg = *(const bf16x8*)(WpT + (size_t)(nbase + nt * 16 + lm) * 1280 + kc + lk);
#pragma unroll
            for (int mt = 0; mt < 4; mt++)
                acc[mt][nt] = __builtin_amdgcn_mfma_f32_16x16x32_bf16(af[mt], bfg, acc[mt][nt], 0, 0, 0);
        }
    }
    float bbv[8];
#pragma unroll
    for (int nt = 0; nt < 8; nt++) bbv[nt] = bp[nbase + nt * 16 + lm];
#pragma unroll
    for (int mt = 0; mt < 4; mt++)
#pragma unroll
        for (int nt = 0; nt < 8; nt++)
#pragma unroll
            for (int r = 0; r < 4; r++) {
                int row = r0 + mt * 16 + lkq * 4 + r;
                int col = nbase + nt * 16 + lm;
                Ab[(size_t)row * 512 + col] = f2b(acc[mt][nt][r] + bbv[nt]);
            }
}

// ---------------------------------------------------------------------------
// P3: c0 = h0 = mean_p Ab (f32); hb0 = bf16(h0). grid 256.
__global__ __launch_bounds__(256) void projmean_kernel(
    const u16* __restrict__ Ab, float* __restrict__ c0, u16* __restrict__ hb0)
{
    const int n = blockIdx.x, tid = threadIdx.x;
    const int col0 = tid, col1 = tid + 256;
    float s0 = 0.f, s1 = 0.f;
#pragma unroll
    for (int p = 0; p < 16; p++) {
        const u16* ap = Ab + ((size_t)n * 16 + p) * 512;
        s0 += b2f(ap[col0]);
        s1 += b2f(ap[col1]);
    }
    s0 *= 0.0625f; s1 *= 0.0625f;
    c0[n * 512 + col0] = s0;  c0[n * 512 + col1] = s1;
    hb0[(size_t)n * 512 + col0] = f2b(s0);
    hb0[(size_t)n * 512 + col1] = f2b(s1);
}

// ---------------------------------------------------------------------------
// K2 (MFMA): xpb = embed@Wx + b  (bf16), rows stored as [t][n]
__global__ __launch_bounds__(256) void xp_mfma_kernel(
    const int* __restrict__ caps, const float* __restrict__ We,
    const u16* __restrict__ Wxt, const float* __restrict__ bb,
    u16* __restrict__ xpb)
{
    const int ct = blockIdx.x, rt = blockIdx.y;
    const int tid = threadIdx.x, w = tid >> 6, lane = tid & 63;
    const int r0 = rt * 64;
    const int lm = lane & 15, lkq = lane >> 4, lk = lkq * 8;
    const int nbase = ct * 512 + w * 128;

    int capm[4];
#pragma unroll
    for (int mt = 0; mt < 4; mt++) {
        int row = r0 + mt * 16 + lm;
        capm[mt] = caps[(row >> 5) * 33 + (row & 31)];
    }
    f32x4 acc[4][8];
#pragma unroll
    for (int mt = 0; mt < 4; mt++)
#pragma unroll
        for (int nt = 0; nt < 8; nt++) acc[mt][nt] = (f32x4){0.f, 0.f, 0.f, 0.f};

    for (int kc = 0; kc < 256; kc += 32) {
        bf16x8 af[4];
#pragma unroll
        for (int mt = 0; mt < 4; mt++) {
            const float* ap = We + (size_t)capm[mt] * 256 + kc + lk;
            float4 f0 = *(const float4*)ap;
            float4 f1 = *(const float4*)(ap + 4);
            bf16x8 t;
            t[0] = (short)f2b(f0.x); t[1] = (short)f2b(f0.y);
            t[2] = (short)f2b(f0.z); t[3] = (short)f2b(f0.w);
            t[4] = (short)f2b(f1.x); t[5] = (short)f2b(f1.y);
            t[6] = (short)f2b(f1.z); t[7] = (short)f2b(f1.w);
            af[mt] = t;
        }
#pragma unroll
        for (int nt = 0; nt < 8; nt++) {
            bf16x8 bfg = *(const bf16x8*)(Wxt + (size_t)(nbase + nt * 16 + lm) * 256 + kc + lk);
#pragma unroll
            for (int mt = 0; mt < 4; mt++)
                acc[mt][nt] = __builtin_amdgcn_mfma_f32_16x16x32_bf16(af[mt], bfg, acc[mt][nt], 0, 0, 0);
        }
    }
    float bbv[8];
#pragma unroll
    for (int nt = 0; nt < 8; nt++) bbv[nt] = bb[nbase + nt * 16 + lm];
#pragma unroll
    for (int mt = 0; mt < 4; mt++)
#pragma unroll
        for (int nt = 0; nt < 8; nt++)
#pragma unroll
            for (int r = 0; r < 4; r++) {
                int row = r0 + mt * 16 + lkq * 4 + r;   // row = n*32 + t
                int col = nbase + nt * 16 + lm;
                float v = acc[mt][nt][r] + bbv[nt];
                xpb[((size_t)(row & 31) * 256 + (row >> 5)) * 2048 + col] = f2b(v);
            }
}

// ---------------------------------------------------------------------------
// K3 (MFMA, once): PreAW[p*256+n][col] = A[n,p,:] @ Wattn  (bf16 out)
__global__ __launch_bounds__(256) void preaw_mfma_kernel(
    const u16* __restrict__ Ab, const u16* __restrict__ what,
    u16* __restrict__ preaw)
{
    const int ct = blockIdx.x, rt = blockIdx.y;
    const int tid = threadIdx.x, w = tid >> 6, lane = tid & 63;
    const int r0 = rt * 64;
    const int lm = lane & 15, lkq = lane >> 4, lk = lkq * 8;
    const int nbase = ct * 512 + w * 128;

    f32x4 acc[4][8];
#pragma unroll
    for (int mt = 0; mt < 4; mt++)
#pragma unroll
        for (int nt = 0; nt < 8; nt++) acc[mt][nt] = (f32x4){0.f, 0.f, 0.f, 0.f};

    for (int kc = 0; kc < 512; kc += 32) {
        bf16x8 af[4];
#pragma unroll
        for (int mt = 0; mt < 4; mt++) {
            int row = r0 + mt * 16 + lm;                  // row = p*256+n
            af[mt] = *(const bf16x8*)(Ab + ((size_t)(row & 255) * 16 + (row >> 8)) * 512 + kc + lk);
        }
#pragma unroll
        for (int nt = 0; nt < 8; nt++) {
            bf16x8 bfg = *(const bf16x8*)(what + (size_t)(nbase + nt * 16 + lm) * 1024 + 512 + kc + lk);
#pragma unroll
            for (int mt = 0; mt < 4; mt++)
                acc[mt][nt] = __builtin_amdgcn_mfma_f32_16x16x32_bf16(af[mt], bfg, acc[mt][nt], 0, 0, 0);
        }
    }
#pragma unroll
    for (int mt = 0; mt < 4; mt++)
#pragma unroll
        for (int nt = 0; nt < 8; nt++)
#pragma unroll
            for (int r = 0; r < 4; r++) {
                int row = r0 + mt * 16 + lkq * 4 + r;
                int col = nbase + nt * 16 + lm;
                preaw[(size_t)row * 2048 + col] = f2b(acc[mt][nt][r]);
            }
}

// ---------------------------------------------------------------------------
// K4 (once): scores for t=0: scp[0][n][p] = h0[n]·A[n,p]; zero cg>0
__global__ __launch_bounds__(64) void score_init_kernel(
    const u16* __restrict__ hb0, const u16* __restrict__ Ab,
    float* __restrict__ scp)
{
    const int n = blockIdx.x, lane = threadIdx.x;
    const u16* hp = hb0 + (size_t)n * 512 + lane * 8;
    ushort4 h0 = *(const ushort4*)hp, h1 = *(const ushort4*)(hp + 4);
    float hv0 = b2f(h0.x), hv1 = b2f(h0.y), hv2 = b2f(h0.z), hv3 = b2f(h0.w);
    float hv4 = b2f(h1.x), hv5 = b2f(h1.y), hv6 = b2f(h1.z), hv7 = b2f(h1.w);
    float mine = 0.f;
#pragma unroll
    for (int p = 0; p < 16; p++) {
        const u16* ap = Ab + (size_t)n * 8192 + p * 512 + lane * 8;
        ushort4 a0 = *(const ushort4*)ap, a1 = *(const ushort4*)(ap + 4);
        float s = hv0*b2f(a0.x) + hv1*b2f(a0.y) + hv2*b2f(a0.z) + hv3*b2f(a0.w)
                + hv4*b2f(a1.x) + hv5*b2f(a1.y) + hv6*b2f(a1.z) + hv7*b2f(a1.w);
#pragma unroll
        for (int mask = 1; mask <= 32; mask <<= 1) s += __shfl_xor(s, mask, 64);
        if (lane == p) mine = s;
    }
    if (lane < 16) scp[n * 16 + lane] = mine;
    for (int i = lane; i < 31 * 16; i += 64)
        scp[(1 + (i >> 4)) * 4096 + n * 16 + (i & 15)] = 0.f;
}

// ---------------------------------------------------------------------------
// K5 (per step): softmax(scores) -> gates MFMA + PreAW attn + nonlin ->
// c,h update -> score partials for t+1. grid (16 rt, 32 cg), 4 waves.
__global__ __launch_bounds__(256) void gates_fused_kernel(
    const u16* __restrict__ hb_in, const float* __restrict__ scp_in,
    const u16* __restrict__ what, const u16* __restrict__ preaw,
    const u16* __restrict__ xpt, const u16* __restrict__ Ab,
    float* __restrict__ c, u16* __restrict__ hb_out,
    u16* __restrict__ hallbt, float* __restrict__ scp_out)
{
    const int rt = blockIdx.x, cg = blockIdx.y;
    const int tid = threadIdx.x, ty = tid >> 6, lane = tid & 63;
    const int lm = lane & 15, lkq = lane >> 4, lk = lkq * 8;
    const int r0 = rt * 16, hc0 = cg * 16;

    __shared__ u16 hs[16 * 520];
    __shared__ float sred[16][17];
    __shared__ float wts[16][17];
    __shared__ float gred[3][64][4];
    __shared__ u16 hnew[16][16];

#pragma unroll
    for (int i = 0; i < 8; i++) {
        int fid = tid + i * 256;
        int r = fid >> 7, c4 = fid & 127;
        *(ushort4*)&hs[r * 520 + c4 * 4] =
            *(const ushort4*)(hb_in + (size_t)(r0 + r) * 512 + c4 * 4);
    }
    {
        const int r = tid >> 4, p = tid & 15;
        float s = 0.f;
#pragma unroll
        for (int g = 0; g < 32; g++) s += scp_in[g * 4096 + (r0 + r) * 16 + p];
        sred[r][p] = s * 0.04419417382415922f;
    }
    __syncthreads();
    {
        const int r = tid >> 4, p = tid & 15;
        float m = -1e30f;
#pragma unroll
        for (int q = 0; q < 16; q++) m = fmaxf(m, sred[r][q]);
        float su = 0.f;
#pragma unroll
        for (int q = 0; q < 16; q++) su += __expf(sred[r][q] - m);
        wts[r][p] = __expf(sred[r][p] - m) / su;
    }
    __syncthreads();

    f32x4 acc = (f32x4){0.f, 0.f, 0.f, 0.f};
    const u16* brow = what + (size_t)(ty * 512 + hc0 + lm) * 1024 + lk;
    const u16* arow = &hs[lm * 520 + lk];
    for (int kc = 0; kc < 512; kc += 32) {
        bf16x8 af = *(const bf16x8*)(arow + kc);
        bf16x8 bfg = *(const bf16x8*)(brow + kc);
        acc = __builtin_amdgcn_mfma_f32_16x16x32_bf16(af, bfg, acc, 0, 0, 0);
    }
    float val[4];
#pragma unroll
    for (int r = 0; r < 4; r++) {
        const int rl = lkq * 4 + r, n = r0 + rl;
        const int col = ty * 512 + hc0 + lm;
        float s = acc[r] + b2f(xpt[(size_t)n * 2048 + col]);
#pragma unroll
        for (int p = 0; p < 16; p++)
            s += wts[rl][p] * b2f(preaw[((size_t)p * 256 + n) * 2048 + col]);
        val[r] = s;
    }
    if (ty > 0) {
#pragma unroll
        for (int r = 0; r < 4; r++) gred[ty - 1][lane][r] = val[r];
    }
    __syncthreads();
    if (ty == 0) {
#pragma unroll
        for (int r = 0; r < 4; r++) {
            const int rl = lkq * 4 + r, n = r0 + rl;
            const int hcol = hc0 + lm;
            float ai  = val[r];
            float af_ = gred[0][lane][r];
            float ao  = gred[1][lane][r];
            float ag  = gred[2][lane][r];
            float ig = 1.f / (1.f + __expf(-ai));
            float fg = 1.f / (1.f + __expf(-af_));
            float og = 1.f / (1.f + __expf(-ao));
            float gv = tanhf(ag);
            const int idx = n * 512 + hcol;
            float cn = fg * c[idx] + ig * gv;
            float hn = og * tanhf(cn);
            c[idx] = cn;
            u16 hbv = f2b(hn);
            hb_out[idx] = hbv;
            hallbt[idx] = hbv;
            hnew[rl][lm] = hbv;
        }
    }
    __syncthreads();
    {
        const int r = tid >> 4, p = tid & 15, n = r0 + r;
        const u16* ap = Ab + (size_t)n * 8192 + p * 512 + hc0;
        float s = 0.f;
#pragma unroll
        for (int j = 0; j < 16; j++) s += b2f(hnew[r][j]) * b2f(ap[j]);
        scp_out[cg * 4096 + n * 16 + p] = s;
    }
}

// ---------------------------------------------------------------------------
// K6 (MFMA v3): vocab + fused logsumexp. 512 thr = 8 waves; block tile
// 64 rows x 512 cols; A staged once in LDS (stride 516), wave acc 4x4.
__global__ __launch_bounds__(512) void vocab_mfma_kernel(
    const u16* __restrict__ hallb, const u16* __restrict__ Wvt,
    const float* __restrict__ bv, const int* __restrict__ caps,
    float* __restrict__ pmax, float* __restrict__ psum, float* __restrict__ tgt)
{
    const int vt = blockIdx.x, rt = blockIdx.y;
    const int tid = threadIdx.x, w = tid >> 6, lane = tid & 63;
    const int r0 = rt * 64;
    const int lm = lane & 15, lkq = lane >> 4, lk = lkq * 8;
    const int nbase = vt * 512 + w * 64;

    __shared__ u16 As[64 * 516];          // 66 KB
    __shared__ int tvs[64];
    __shared__ float cm[64][8], cs[64][8];

#pragma unroll
    for (int i = 0; i < 16; i++) {
        int fid = tid + i * 512;          // 8192 ushort4
        int r = fid >> 7, c4 = (fid & 127) * 4;
        *(ushort4*)&As[r * 516 + c4] = *(const ushort4*)(hallb + (size_t)(r0 + r) * 512 + c4);
    }
    if (tid < 64) {
        int row = r0 + tid;                              // row = t*256 + n
        tvs[tid] = caps[(row & 255) * 33 + (row >> 8) + 1];
    }
    __syncthreads();

    f32x4 acc[4][4];
#pragma unroll
    for (int mt = 0; mt < 4; mt++)
#pragma unroll
        for (int nt = 0; nt < 4; nt++) acc[mt][nt] = (f32x4){0.f, 0.f, 0.f, 0.f};

    for (int kc = 0; kc < 512; kc += 32) {
        bf16x8 af[4];
#pragma unroll
        for (int mt = 0; mt < 4; mt++)
            af[mt] = *(const bf16x8*)&As[(mt * 16 + lm) * 516 + kc + lk];
#pragma unroll
        for (int nt = 0; nt < 4; nt++) {
            bf16x8 bfg = *(const bf16x8*)(Wvt + (size_t)(nbase + nt * 16 + lm) * 512 + kc + lk);
#pragma unroll
            for (int mt = 0; mt < 4; mt++)
                acc[mt][nt] = __builtin_amdgcn_mfma_f32_16x16x32_bf16(af[mt], bfg, acc[mt][nt], 0, 0, 0);
        }
    }

    float bvv[4]; bool vld[4];
#pragma unroll
    for (int nt = 0; nt < 4; nt++) {
        int col = nbase + nt * 16 + lm;
        vld[nt] = (col < NV);
        bvv[nt] = vld[nt] ? bv[col] : 0.f;
    }
#pragma unroll
    for (int mt = 0; mt < 4; mt++)
#pragma unroll
        for (int r = 0; r < 4; r++) {
            int rloc = mt * 16 + lkq * 4 + r;
            int row = r0 + rloc;
            int tv = tvs[rloc];
            float vals[4]; float m = -1e30f;
#pragma unroll
            for (int nt = 0; nt < 4; nt++) {
                int col = nbase + nt * 16 + lm;
                float v = vld[nt] ? (acc[mt][nt][r] + bvv[nt]) : -1e30f;
                vals[nt] = v;
                m = fmaxf(m, v);
                if (col == tv) tgt[row] = v;
            }
#pragma unroll
            for (int mask = 1; mask <= 8; mask <<= 1) m = fmaxf(m, __shfl_xor(m, mask, 64));
            float s = 0.f;
#pragma unroll
            for (int nt = 0; nt < 4; nt++) s += __expf(vals[nt] - m);
#pragma unroll
            for (int mask = 1; mask <= 8; mask <<= 1) s += __shfl_xor(s, mask, 64);
            if (lm == 0) { cm[rloc][w] = m; cs[rloc][w] = s; }
        }
    __syncthreads();
    if (tid < 64) {
        int row = r0 + tid;
        float M = -1e30f;
#pragma unroll
        for (int q = 0; q < 8; q++) M = fmaxf(M, cm[tid][q]);
        float S = 0.f;
#pragma unroll
        for (int q = 0; q < 8; q++) S += cs[tid][q] * __expf(cm[tid][q] - M);
        pmax[row * VT_N + vt] = M;
        psum[row * VT_N + vt] = S;
    }
}

// ---------------------------------------------------------------------------
__global__ __launch_bounds__(256) void loss_reduce_kernel(
    const float* __restrict__ pmax, const float* __restrict__ psum,
    const float* __restrict__ tgt, const int* __restrict__ caps,
    float* __restrict__ loss)
{
    const int row = blockIdx.x * 256 + threadIdx.x;
    float nll = 0.f;
    const int t = row >> 8, n = row & 255;
    const int tv = caps[n * 33 + t + 1];
    if (tv != 0) {
        float M = -1e30f;
#pragma unroll
        for (int vt = 0; vt < VT_N; vt++) M = fmaxf(M, pmax[row * VT_N + vt]);
        float S = 0.f;
#pragma unroll
        for (int vt = 0; vt < VT_N; vt++) S += psum[row * VT_N + vt] * __expf(pmax[row * VT_N + vt] - M);
        nll = logf(S) + M - tgt[row];
    }
#pragma unroll
    for (int off = 32; off; off >>= 1) nll += __shfl_down(nll, off, 64);
    __shared__ float r4[4];
    if ((threadIdx.x & 63) == 0) r4[threadIdx.x >> 6] = nll;
    __syncthreads();
    if (threadIdx.x == 0)
        atomicAdd(loss, (r4[0] + r4[1] + r4[2] + r4[3]) * (1.f / 256.f));
}

__global__ void finalize_kernel(const float* __restrict__ loss, float* __restrict__ out)
{
    if (threadIdx.x == 0 && blockIdx.x == 0) out[0] = loss[0];
}

// ---------------------------------------------------------------------------
extern "C" void kernel_launch(void* const* d_in, const int* in_sizes, int n_in,
                              void* d_out, int out_size, void* d_ws, size_t ws_size,
                              hipStream_t stream) {
    const float* feats = (const float*)d_in[0];
    const int*   caps  = (const int*)d_in[1];
    const float* Wp    = (const float*)d_in[2];
    const float* bp    = (const float*)d_in[3];
    const float* We    = (const float*)d_in[4];
    const float* Wx    = (const float*)d_in[5];
    const float* Wh    = (const float*)d_in[6];
    const float* Wattn = (const float*)d_in[7];
    const float* bb    = (const float*)d_in[8];
    const float* Wv    = (const float*)d_in[9];
    const float* bv    = (const float*)d_in[10];

    char* ws = (char*)d_ws;
    float* c     = (float*)(ws + B_C);
    float* scp0  = (float*)(ws + B_SCP);
    float* scp1  = scp0 + (size_t)32 * 4096;
    float* pmax  = (float*)(ws + B_PMAX);
    float* psum  = (float*)(ws + B_PSUM);
    float* tgt   = (float*)(ws + B_TGT);
    float* loss  = (float*)(ws + B_LOSS);
    u16*   Ab    = (u16*)(ws + B_AB);
    u16*   xpb   = (u16*)(ws + B_XPB);
    u16*   hallb = (u16*)(ws + B_HALLB);
    u16*   wvt   = (u16*)(ws + B_WVT);
    u16*   wxt   = (u16*)(ws + B_WXT);
    u16*   what  = (u16*)(ws + B_WHAT);
    u16*   hb[2] = { (u16*)(ws + B_HB0), (u16*)(ws + B_HB1) };
    u16*   preaw = (u16*)(ws + B_PREAW);
    u16*   fT    = wvt;      // alias: dead before tconv(Wv) overwrites
    u16*   WpT   = xpb;      // alias: dead before xp_mfma overwrites

    hipMemsetAsync(loss, 0, sizeof(float), stream);

    // --- proj path (MFMA): feats^T -> GEMM -> Ab, mean -> c0/hb0 ---
    ftrans_kernel<<<dim3(20, 256), 256, 0, stream>>>(feats, fT);
    tconv_kernel<<<dim3(8, 20), 256, 0, stream>>>(Wp, WpT, 1280, 512, 512, 1280, 0);
    proj_gemm_kernel<<<64, 256, 0, stream>>>(fT, WpT, bp, Ab);
    projmean_kernel<<<256, 256, 0, stream>>>(Ab, c, hb[0]);

    // --- weight preps (overwrite fT / WpT aliases) ---
    tconv_kernel<<<dim3(160, 8), 256, 0, stream>>>(Wv, wvt, 512, NV, NVP, 512, 0);
    tconv_kernel<<<dim3(32, 4),  256, 0, stream>>>(Wx, wxt, 256, 2048, 2048, 256, 0);
    tconv_kernel<<<dim3(32, 8),  256, 0, stream>>>(Wh, what, 512, 2048, 2048, 1024, 0);
    tconv_kernel<<<dim3(32, 8),  256, 0, stream>>>(Wattn, what, 512, 2048, 2048, 1024, 512);
    xp_mfma_kernel<<<dim3(4, 128), 256, 0, stream>>>(caps, We, wxt, bb, xpb);
    preaw_mfma_kernel<<<dim3(4, 64), 256, 0, stream>>>(Ab, what, preaw);
    score_init_kernel<<<256, 64, 0, stream>>>(hb[0], Ab, scp0);

    for (int t = 0; t < NT; t++) {
        const int in = t & 1;
        gates_fused_kernel<<<dim3(16, 32), 256, 0, stream>>>(
            hb[in], in ? scp1 : scp0, what, preaw,
            xpb + (size_t)t * 524288, Ab, c,
            hb[1 - in], hallb + (size_t)t * 131072,
            in ? scp0 : scp1);
    }

    vocab_mfma_kernel<<<dim3(VT_N, 128), 512, 0, stream>>>(
        hallb, wvt, bv, caps, pmax, psum, tgt);
    loss_reduce_kernel<<<32, 256, 0, stream>>>(pmax, psum, tgt, caps, loss);
    finalize_kernel<<<1, 64, 0, stream>>>(loss, (float*)d_out);
}